// Round 3
// baseline (7454.611 us; speedup 1.0000x reference)
//
#include <hip/hip_runtime.h>
#include <hip/hip_bf16.h>
#include <math.h>

typedef short short8 __attribute__((ext_vector_type(8)));
typedef short short4v __attribute__((ext_vector_type(4)));
typedef float f32x4 __attribute__((ext_vector_type(4)));

#define DEVI __device__ __forceinline__

DEVI float bf2f(short s){ union{unsigned u; float f;} x; x.u = ((unsigned)(unsigned short)s) << 16; return x.f; }

// V=32000 H=1024 S=512 B=16 T=128, SOS=1
// ws layout (bytes)
constexpr size_t o_wout   = 0;                          // bf16 [32000*1024] (65,536,000 B)
constexpr size_t o_encbf  = 0;                          // overlay (dead before wout used)
constexpr size_t o_kbf    = 16777216;                   // overlay
constexpr size_t o_wkbf   = 33554432;                   // overlay
constexpr size_t o_wvbf   = 35651584;                   // overlay
constexpr size_t o_wqtbf  = 37748736;                   // overlay
constexpr size_t o_vt     = 41943040;                   // overlay: bf16 VT [16][1024][512] (16MB)
constexpr size_t o_kq     = 65536000;                   // bf16 [8192*1024]
constexpr size_t o_vbf    = o_kq    + 16777216;         // bf16 [8192*1024]
constexpr size_t o_wih2   = o_vbf   + 16777216;         // bf16 [4096*1024]
constexpr size_t o_whh    = o_wih2  + 8388608;          // bf16 [4096*1024]
constexpr size_t o_hall   = o_whh   + 8388608;          // bf16 [2048*1024]
constexpr size_t o_gconst = o_hall  + 4194304;          // f32 [4096]
constexpr size_t o_sb     = o_gconst+ 16384;            // f32 [8192]
constexpr size_t o_hg     = o_sb    + 32768;            // bf16 [16*1024] current h
constexpr size_t o_ctxn   = o_hg    + 32768;            // bf16 [16*1024] normalized ctx
constexpr size_t o_eg     = o_ctxn  + 32768;            // f32 [16*512] exp scores
constexpr size_t o_bar    = o_eg    + 32768;            // u32 barrier

// ---------------- elementwise converts ----------------
__global__ void k_convert(const float* __restrict__ src, __hip_bfloat16* __restrict__ dst, int n){
  int i = (blockIdx.x*blockDim.x + threadIdx.x)*4;
  int stride = gridDim.x*blockDim.x*4;
  for (; i < n; i += stride){
    float4 v = *(const float4*)(src+i);
    __hip_bfloat16 o[4] = {__float2bfloat16(v.x),__float2bfloat16(v.y),__float2bfloat16(v.z),__float2bfloat16(v.w)};
    *(short4v*)(dst+i) = *(const short4v*)o;
  }
}

// Wq [1024][1024] f32 -> WqT bf16 (dst[h][d] = src[d][h])
__global__ void k_tcvt(const float* __restrict__ src, __hip_bfloat16* __restrict__ dst){
  __shared__ float tile[64][65];
  int i0 = blockIdx.y*64, j0 = blockIdx.x*64;
  int tr = threadIdx.x >> 6, tc = threadIdx.x & 63;
  for (int p=0;p<16;p++){ int r = p*4 + tr; tile[r][tc] = src[(size_t)(i0+r)*1024 + j0+tc]; }
  __syncthreads();
  for (int p=0;p<16;p++){ int r = p*4 + tr; dst[(size_t)(j0+r)*1024 + i0+tc] = __float2bfloat16(tile[tc][r]); }
}

// Wih2[r][c] = W_ih[r][1024+c], r<4096
__global__ void k_extract(const float* __restrict__ src, __hip_bfloat16* __restrict__ dst){
  int i = blockIdx.x*blockDim.x + threadIdx.x;
  int stride = gridDim.x*blockDim.x;
  for (; i < 4096*1024; i += stride){
    int r = i >> 10, c = i & 1023;
    dst[i] = __float2bfloat16(src[((size_t)r << 11) + 1024 + c]);
  }
}

__global__ void k_init(const float* __restrict__ eh, __hip_bfloat16* __restrict__ hg,
                       unsigned* __restrict__ bar){
  int i = blockIdx.x*blockDim.x + threadIdx.x;
  if (i < 16384) hg[i] = __float2bfloat16(eh[i]);
  if (i == 0) *bar = 0u;
}

// gate_const[n] = b_ih[n] + b_hh[n] + emb[SOS]·W_ih[n, 0:1024]
__global__ void k_gconst(const float* __restrict__ emb, const float* __restrict__ Wih,
                         const float* __restrict__ bih, const float* __restrict__ bhh,
                         float* __restrict__ gc){
  int w = threadIdx.x >> 6, lane = threadIdx.x & 63;
  int n = blockIdx.x*4 + w;
  const float* er = emb + 1024;  // SOS = 1
  const float* wr = Wih + (size_t)n*2048;
  float acc = 0.f;
  for (int q=0;q<16;q++){ int k = lane*16+q; acc += er[k]*wr[k]; }
  for (int off=32; off; off>>=1) acc += __shfl_xor(acc, off);
  if (lane==0) gc[n] = acc + bih[n] + bhh[n];
}

// sb[r] = (bq · K[r,:]) / 32
__global__ void k_sb(const __hip_bfloat16* __restrict__ Kb, const float* __restrict__ bq,
                     float* __restrict__ sb){
  int w = threadIdx.x >> 6, lane = threadIdx.x & 63;
  int r = blockIdx.x*4 + w;
  const __hip_bfloat16* kr = Kb + (size_t)r*1024;
  float acc = 0.f;
  for (int q=0;q<16;q++){ int k = lane*16+q; acc += __bfloat162float(kr[k])*bq[k]; }
  for (int off=32; off; off>>=1) acc += __shfl_xor(acc, off);
  if (lane==0) sb[r] = acc * 0.03125f;
}

// V [16*512][1024] -> VT [16][1024][512]
__global__ void k_vtrans(const __hip_bfloat16* __restrict__ V, __hip_bfloat16* __restrict__ VT){
  __shared__ short t[64][65];
  int b = blockIdx.z, s0 = blockIdx.y*64, h0 = blockIdx.x*64;
  int r = threadIdx.x >> 6, c = threadIdx.x & 63;
  const short* vp = (const short*)V + ((size_t)(b*512 + s0))*1024 + h0;
  #pragma unroll
  for (int p=0;p<16;p++) t[p*4+r][c] = vp[(size_t)(p*4+r)*1024 + c];
  __syncthreads();
  short* op = (short*)VT + ((size_t)(b*1024 + h0))*512 + s0;
  #pragma unroll
  for (int p=0;p<16;p++) op[(size_t)(p*4+r)*512 + c] = t[c][p*4+r];
}

// ---------------- GEMM: C = scale*(A @ B^T) + bias ----------------
template<int EPI>
__global__ __launch_bounds__(256) void k_gemm(const __hip_bfloat16* __restrict__ A,
    const __hip_bfloat16* __restrict__ Bm, const float* __restrict__ bias,
    void* __restrict__ Cp, int M, int N, int K, float scale){
  __shared__ __hip_bfloat16 sA[128*40];
  __shared__ __hip_bfloat16 sB[128*40];
  int tid = threadIdx.x;
  int lane = tid & 63, w = tid >> 6;
  int wr = w >> 1, wc = w & 1;
  int m0 = blockIdx.y*128, n0 = blockIdx.x*128;
  int lrow = lane & 15, lk = lane >> 4;
  f32x4 acc[4][4] = {};
  for (int k0 = 0; k0 < K; k0 += 32){
    __syncthreads();
    #pragma unroll
    for (int l0 = 0; l0 < 1024; l0 += 256){
      int l = l0 + tid;
      int half = l >> 9;
      int ch = l & 511;
      int row = ch >> 2, seg = ch & 3;
      const __hip_bfloat16* src = half ? (Bm + (size_t)(n0+row)*K + k0 + seg*8)
                                       : (A  + (size_t)(m0+row)*K + k0 + seg*8);
      __hip_bfloat16* dst = (half ? sB : sA) + row*40 + seg*8;
      *(short8*)dst = *(const short8*)src;
    }
    __syncthreads();
    short8 af[4], bfq[4];
    #pragma unroll
    for (int mi=0;mi<4;mi++) af[mi]  = *(short8*)(sA + (wr*64+mi*16+lrow)*40 + lk*8);
    #pragma unroll
    for (int ni=0;ni<4;ni++) bfq[ni] = *(short8*)(sB + (wc*64+ni*16+lrow)*40 + lk*8);
    #pragma unroll
    for (int mi=0;mi<4;mi++)
      #pragma unroll
      for (int ni=0;ni<4;ni++)
        acc[mi][ni] = __builtin_amdgcn_mfma_f32_16x16x32_bf16(af[mi], bfq[ni], acc[mi][ni], 0,0,0);
  }
  int crow0 = (lane>>4)*4;
  int ccol = lane & 15;
  #pragma unroll
  for (int mi=0;mi<4;mi++)
    #pragma unroll
    for (int ni=0;ni<4;ni++){
      int gn = n0 + wc*64 + ni*16 + ccol;
      float bv = bias ? bias[gn] : 0.0f;
      #pragma unroll
      for (int j=0;j<4;j++){
        int gm = m0 + wr*64 + mi*16 + crow0 + j;
        float v = acc[mi][ni][j]*scale + bv;
        if (EPI==0){
          ((__hip_bfloat16*)Cp)[(size_t)gm*N + gn] = __float2bfloat16(v);
        } else {
          int tt = gm >> 4, bb = gm & 15;
          ((float*)Cp)[(size_t)(bb*128+tt)*N + gn] = v;
        }
      }
    }
}

// ---------------- grid barrier ----------------
DEVI void gsync(unsigned* bar, unsigned target){
  __syncthreads();
  if (threadIdx.x == 0){
    __threadfence();
    __hip_atomic_fetch_add(bar, 1u, __ATOMIC_RELAXED, __HIP_MEMORY_SCOPE_AGENT);
    while (__hip_atomic_load(bar, __ATOMIC_RELAXED, __HIP_MEMORY_SCOPE_AGENT) < target)
      __builtin_amdgcn_s_sleep(4);
    __threadfence();
  }
  __syncthreads();
}

// ---------------- persistent decoder ----------------
// 256 blocks x 256 threads, cooperative. Block c: attention slice (b=c>>4, i=c&15)
// owning KQ[b, 32i..32i+32) and VT[b, 64i..64i+64), plus gate slice j in [4c,4c+4).
__global__ __launch_bounds__(256, 1) void k_decode(
    const __hip_bfloat16* __restrict__ KQ, const __hip_bfloat16* __restrict__ VT,
    const float* __restrict__ sb, const __hip_bfloat16* __restrict__ Whh,
    const __hip_bfloat16* __restrict__ Wih2, const float* __restrict__ gconst,
    const float* __restrict__ ec,
    __hip_bfloat16* __restrict__ hglob, float* __restrict__ eg,
    __hip_bfloat16* __restrict__ ctxn, __hip_bfloat16* __restrict__ hall,
    float* __restrict__ outH, float* __restrict__ outC, unsigned* __restrict__ bar)
{
  __shared__ __attribute__((aligned(16))) __hip_bfloat16 hL[16*1024]; // swizzled rows of 2048B
  __shared__ __attribute__((aligned(16))) float eL[528];              // padded e row
  __shared__ __attribute__((aligned(16))) float sP[4][324];           // wave gate partials [col*20+b]
  __shared__ float sG[256];                                           // gates [b][r]
  __shared__ float sRed[4];
  __shared__ __attribute__((aligned(16))) __hip_bfloat16 sCtx[64];
  __shared__ float sSb[32];
  __shared__ float sGc[16];

  const int tid = threadIdx.x;
  const int lane = tid & 63, w = tid >> 6;
  const int l16 = lane & 15, lhi = lane >> 4;
  const int blk = blockIdx.x;
  const int bown = blk >> 4, iown = blk & 15;
  const int j0 = blk * 4;

  // gate-weight fragments, resident in registers for all 128 steps
  const int nrow = (l16 >> 2) * 1024 + j0 + (l16 & 3);
  short8 wh[8], wi[8];
  {
    const __hip_bfloat16* whp = Whh + (size_t)nrow*1024 + w*256 + lhi*8;
    const __hip_bfloat16* wip = Wih2 + (size_t)nrow*1024 + w*256 + lhi*8;
    #pragma unroll
    for (int kk = 0; kk < 8; kk++){
      wh[kk] = *(const short8*)(whp + kk*32);
      wi[kk] = *(const short8*)(wip + kk*32);
    }
  }
  if (tid < 32) sSb[tid] = sb[bown*512 + iown*32 + tid];
  if (tid < 16) sGc[tid] = gconst[(tid>>2)*1024 + j0 + (tid&3)];
  float creg = 0.f;
  const int cb = tid >> 2, cj = j0 + (tid & 3);
  if (tid < 64) creg = ec[cb*1024 + cj];

  unsigned gen = 0;
  const int xro = (bown & 7) << 4;
  const __hip_bfloat16* kqBlk = KQ + ((size_t)(bown*512 + iown*32))*1024;

  for (int t = 0; t < 128; ++t){
    // ---- phase A: load h (swizzled), scores -> e, gh MFMA ----
    #pragma unroll
    for (int m8 = 0; m8 < 8; m8++){
      int m = m8*256 + tid;            // 0..2047 : 16 rows x 128 short8-segments
      int bb = m >> 7, seg = m & 127;
      short8 v = *(const short8*)(hglob + bb*1024 + seg*8);
      *(short8*)((char*)hL + bb*2048 + ((seg*16) ^ ((bb & 7) << 4))) = v;
    }
    __syncthreads();
    {
      int row = tid >> 3, kx = tid & 7;
      const __hip_bfloat16* kp = kqBlk + (size_t)row*1024 + kx*8;
      const char* hp = (const char*)hL + bown*2048;
      float acc = 0.f;
      #pragma unroll
      for (int q = 0; q < 16; q++){
        short8 kv = *(const short8*)(kp + q*64);
        short8 hv = *(const short8*)(hp + (((kx*16 + q*128)) ^ xro));
        #pragma unroll
        for (int e2 = 0; e2 < 8; e2++) acc += bf2f(hv[e2]) * bf2f(kv[e2]);
      }
      acc += __shfl_xor(acc, 1); acc += __shfl_xor(acc, 2); acc += __shfl_xor(acc, 4);
      if (kx == 0) eg[bown*512 + iown*32 + row] = expf(acc + sSb[row]);
    }
    f32x4 gacc = {};
    {
      const char* hb = (const char*)hL + l16*2048;
      const int xr = (l16 & 7) << 4;
      const int kbase = w*512 + lhi*16;
      #pragma unroll
      for (int kk = 0; kk < 8; kk++){
        short8 hf = *(const short8*)(hb + ((kbase + kk*64) ^ xr));
        gacc = __builtin_amdgcn_mfma_f32_16x16x32_bf16(hf, wh[kk], gacc, 0,0,0);
      }
    }
    gen++; gsync(bar, gen*256u);

    // ---- phase B: e -> L, ctx slice ----
    {
      float ep0 = eg[bown*512 + tid];
      int s1 = tid + 256;
      float ep1 = eg[bown*512 + s1];
      eL[tid + ((tid>>7)<<2)] = ep0;
      eL[s1 + ((s1>>7)<<2)] = ep1;
      float lp = ep0 + ep1;
      for (int off=32; off; off>>=1) lp += __shfl_xor(lp, off);
      if (lane == 0) sRed[w] = lp;
    }
    __syncthreads();
    {
      float Linv = 1.0f/(sRed[0]+sRed[1]+sRed[2]+sRed[3]);
      int hloc = tid >> 2, sc = (tid & 3)*128;
      const __hip_bfloat16* vp = VT + ((size_t)(bown*1024 + iown*64 + hloc))*512 + sc;
      const float* ep = eL + sc + ((sc>>7)<<2);
      float a = 0.f;
      #pragma unroll
      for (int q = 0; q < 16; q++){
        short8 vv = *(const short8*)(vp + q*8);
        float4 e0 = *(const float4*)(ep + q*8);
        float4 e1 = *(const float4*)(ep + q*8 + 4);
        a += e0.x*bf2f(vv[0]) + e0.y*bf2f(vv[1]) + e0.z*bf2f(vv[2]) + e0.w*bf2f(vv[3]);
        a += e1.x*bf2f(vv[4]) + e1.y*bf2f(vv[5]) + e1.z*bf2f(vv[6]) + e1.w*bf2f(vv[7]);
      }
      a += __shfl_xor(a, 1); a += __shfl_xor(a, 2);
      if ((tid & 3) == 0) sCtx[hloc] = __float2bfloat16(a * Linv);
    }
    __syncthreads();
    if (tid < 8) *(short8*)(ctxn + bown*1024 + iown*64 + tid*8) = *(const short8*)(sCtx + tid*8);
    gen++; gsync(bar, gen*256u);

    // ---- phase C: load ctx (swizzled), gctx MFMA, gates, LSTM ----
    #pragma unroll
    for (int m8 = 0; m8 < 8; m8++){
      int m = m8*256 + tid;
      int bb = m >> 7, seg = m & 127;
      short8 v = *(const short8*)(ctxn + bb*1024 + seg*8);
      *(short8*)((char*)hL + bb*2048 + ((seg*16) ^ ((bb & 7) << 4))) = v;
    }
    __syncthreads();
    {
      const char* hb = (const char*)hL + l16*2048;
      const int xr = (l16 & 7) << 4;
      const int kbase = w*512 + lhi*16;
      #pragma unroll
      for (int kk = 0; kk < 8; kk++){
        short8 cf = *(const short8*)(hb + ((kbase + kk*64) ^ xr));
        gacc = __builtin_amdgcn_mfma_f32_16x16x32_bf16(cf, wi[kk], gacc, 0,0,0);
      }
    }
    *(f32x4*)(&sP[w][l16*20 + lhi*4]) = gacc;
    __syncthreads();
    {
      int rr = tid >> 4, bb = tid & 15;
      float gv = sGc[rr] + sP[0][rr*20+bb] + sP[1][rr*20+bb] + sP[2][rr*20+bb] + sP[3][rr*20+bb];
      sG[bb*16 + rr] = gv;
    }
    __syncthreads();
    if (tid < 64){
      int jj = tid & 3;
      float gi = sG[cb*16 + jj];
      float gf = sG[cb*16 + 4 + jj];
      float gg = sG[cb*16 + 8 + jj];
      float go = sG[cb*16 + 12 + jj];
      float si = 1.f/(1.f+expf(-gi));
      float sf = 1.f/(1.f+expf(-gf));
      float so = 1.f/(1.f+expf(-go));
      float c2 = sf*creg + si*tanhf(gg);
      float h2 = so*tanhf(c2);
      creg = c2;
      __hip_bfloat16 hbv = __float2bfloat16(h2);
      hglob[cb*1024 + cj] = hbv;
      hall[((size_t)(t*16 + cb))*1024 + cj] = hbv;
      if (t == 127){ outH[cb*1024+cj] = h2; outC[cb*1024+cj] = c2; }
    }
    gen++; gsync(bar, gen*256u);
  }
}

// ---------------- in-place log-softmax over rows of 32000 ----------------
__global__ __launch_bounds__(256) void k_logsm(float* __restrict__ out){
  int row = blockIdx.x;
  float* p = out + (size_t)row*32000;
  int tid = threadIdx.x;
  __shared__ float red[4];
  float s = 0.f;
  for (int i = tid*4; i < 32000; i += 1024){
    float4 v = *(float4*)(p+i);
    s += __expf(v.x)+__expf(v.y)+__expf(v.z)+__expf(v.w);
  }
  for (int off=32; off; off>>=1) s += __shfl_xor(s, off);
  if ((tid&63)==0) red[tid>>6] = s;
  __syncthreads();
  float L = logf(red[0]+red[1]+red[2]+red[3]);
  for (int i = tid*4; i < 32000; i += 1024){
    float4 v = *(float4*)(p+i);
    v.x-=L; v.y-=L; v.z-=L; v.w-=L;
    *(float4*)(p+i) = v;
  }
}

extern "C" void kernel_launch(void* const* d_in, const int* in_sizes, int n_in,
                              void* d_out, int out_size, void* d_ws, size_t ws_size,
                              hipStream_t stream){
  const float* enc = (const float*)d_in[0];
  const float* eh  = (const float*)d_in[1];
  const float* ec  = (const float*)d_in[2];
  const float* emb = (const float*)d_in[3];
  const float* Wq  = (const float*)d_in[4];
  const float* bq  = (const float*)d_in[5];
  const float* Wk  = (const float*)d_in[6];
  const float* bk  = (const float*)d_in[7];
  const float* Wv  = (const float*)d_in[8];
  const float* bv  = (const float*)d_in[9];
  const float* Wih = (const float*)d_in[10];
  const float* bih = (const float*)d_in[11];
  const float* Whh = (const float*)d_in[12];
  const float* bhh = (const float*)d_in[13];
  const float* Wo  = (const float*)d_in[14];
  const float* bo  = (const float*)d_in[15];

  char* ws = (char*)d_ws;
  __hip_bfloat16* encbf = (__hip_bfloat16*)(ws + o_encbf);
  __hip_bfloat16* kbf   = (__hip_bfloat16*)(ws + o_kbf);
  __hip_bfloat16* wkbf  = (__hip_bfloat16*)(ws + o_wkbf);
  __hip_bfloat16* wvbf  = (__hip_bfloat16*)(ws + o_wvbf);
  __hip_bfloat16* wqtbf = (__hip_bfloat16*)(ws + o_wqtbf);
  __hip_bfloat16* vt    = (__hip_bfloat16*)(ws + o_vt);
  __hip_bfloat16* woutbf= (__hip_bfloat16*)(ws + o_wout);
  __hip_bfloat16* kq    = (__hip_bfloat16*)(ws + o_kq);
  __hip_bfloat16* vbf   = (__hip_bfloat16*)(ws + o_vbf);
  __hip_bfloat16* wih2  = (__hip_bfloat16*)(ws + o_wih2);
  __hip_bfloat16* whhbf = (__hip_bfloat16*)(ws + o_whh);
  __hip_bfloat16* hall  = (__hip_bfloat16*)(ws + o_hall);
  float* gconst = (float*)(ws + o_gconst);
  float* sbp    = (float*)(ws + o_sb);
  __hip_bfloat16* hglob = (__hip_bfloat16*)(ws + o_hg);
  __hip_bfloat16* ctxn  = (__hip_bfloat16*)(ws + o_ctxn);
  float* eg     = (float*)(ws + o_eg);
  unsigned* bar = (unsigned*)(ws + o_bar);
  float* outP   = (float*)d_out;
  float* outH   = outP + 65536000;
  float* outC   = outH + 16384;

  // ---- precompute ----
  k_convert<<<1024,256,0,stream>>>(enc, encbf, 8388608);
  k_convert<<<256,256,0,stream>>>(Wk, wkbf, 1048576);
  k_convert<<<256,256,0,stream>>>(Wv, wvbf, 1048576);
  k_tcvt<<<dim3(16,16),256,0,stream>>>(Wq, wqtbf);
  k_gemm<0><<<dim3(8,64),256,0,stream>>>(encbf, wkbf, bk, kbf, 8192,1024,1024, 1.f);
  k_gemm<0><<<dim3(8,64),256,0,stream>>>(encbf, wvbf, bv, vbf, 8192,1024,1024, 1.f);
  k_gemm<0><<<dim3(8,64),256,0,stream>>>(kbf, wqtbf, (const float*)nullptr, kq, 8192,1024,1024, 0.03125f);
  k_vtrans<<<dim3(16,8,16),256,0,stream>>>(vbf, vt);
  k_sb<<<2048,256,0,stream>>>(kbf, bq, sbp);
  k_extract<<<1024,256,0,stream>>>(Wih, wih2);
  k_convert<<<1024,256,0,stream>>>(Whh, whhbf, 4194304);
  k_gconst<<<1024,256,0,stream>>>(emb, Wih, bih, bhh, gconst);
  k_init<<<64,256,0,stream>>>(eh, hglob, bar);

  // ---- recurrence: persistent cooperative kernel ----
  {
    const __hip_bfloat16* a_kq = kq; const __hip_bfloat16* a_vt = vt;
    const float* a_sb = sbp; const __hip_bfloat16* a_whh = whhbf;
    const __hip_bfloat16* a_wih = wih2; const float* a_gc = gconst;
    const float* a_ec = ec;
    __hip_bfloat16* a_hg = hglob; float* a_eg = eg;
    __hip_bfloat16* a_cx = ctxn; __hip_bfloat16* a_ha = hall;
    float* a_oh = outH; float* a_oc = outC; unsigned* a_bar = bar;
    void* args[] = { &a_kq, &a_vt, &a_sb, &a_whh, &a_wih, &a_gc, &a_ec,
                     &a_hg, &a_eg, &a_cx, &a_ha, &a_oh, &a_oc, &a_bar };
    hipError_t err = hipLaunchCooperativeKernel((void*)k_decode, dim3(256), dim3(256),
                                                args, 0u, stream);
    if (err != hipSuccess){
      // fallback: plain launch (256 blocks <= 256 CUs, 1 block/CU -> co-resident)
      k_decode<<<256,256,0,stream>>>(kq, vt, sbp, whhbf, wih2, gconst, ec,
                                     hglob, eg, ctxn, hall, outH, outC, bar);
    }
  }

  // ---- logits + log-softmax ----
  k_convert<<<2048,256,0,stream>>>(Wo, woutbf, 32768000);
  k_gemm<1><<<dim3(250,16),256,0,stream>>>(hall, woutbf, bo, d_out, 2048,32000,1024, 1.f);
  k_logsm<<<2048,256,0,stream>>>(outP);
}

// Round 4
// 5778.296 us; speedup vs baseline: 1.2901x; 1.2901x over previous
//
#include <hip/hip_runtime.h>
#include <hip/hip_bf16.h>
#include <math.h>

typedef short short8 __attribute__((ext_vector_type(8)));
typedef short short4v __attribute__((ext_vector_type(4)));
typedef float f32x4 __attribute__((ext_vector_type(4)));

#define DEVI __device__ __forceinline__

DEVI float bf2f(short s){ union{unsigned u; float f;} x; x.u = ((unsigned)(unsigned short)s) << 16; return x.f; }

// V=32000 H=1024 S=512 B=16 T=128, SOS=1
// ws layout (bytes)
constexpr size_t o_wout   = 0;                          // bf16 [32000*1024]
constexpr size_t o_encbf  = 0;                          // overlay (dead before wout used)
constexpr size_t o_kbf    = 16777216;                   // overlay
constexpr size_t o_wkbf   = 33554432;                   // overlay
constexpr size_t o_wvbf   = 35651584;                   // overlay
constexpr size_t o_wqtbf  = 37748736;                   // overlay
constexpr size_t o_vt     = 41943040;                   // overlay: bf16 VT [16][1024][512]
constexpr size_t o_kq     = 65536000;                   // bf16 [8192*1024]
constexpr size_t o_vbf    = o_kq    + 16777216;         // bf16 [8192*1024]
constexpr size_t o_wih2   = o_vbf   + 16777216;         // bf16 [4096*1024]
constexpr size_t o_whh    = o_wih2  + 8388608;          // bf16 [4096*1024]
constexpr size_t o_hall   = o_whh   + 8388608;          // bf16 [2048*1024]
constexpr size_t o_gconst = o_hall  + 4194304;          // f32 [4096]
constexpr size_t o_sb     = o_gconst+ 16384;            // f32 [8192]
constexpr size_t o_hg     = o_sb    + 32768;            // bf16 [16*1024] current h
constexpr size_t o_ctxn   = o_hg    + 32768;            // bf16 [16*1024] normalized ctx
constexpr size_t o_eg     = o_ctxn  + 32768;            // f32 [16*512] exp scores
constexpr size_t o_bar    = o_eg    + 32768;            // u32 counters: 4 group (256B stride) + 16 batch (256B stride)

// ---------------- elementwise converts ----------------
__global__ void k_convert(const float* __restrict__ src, __hip_bfloat16* __restrict__ dst, int n){
  int i = (blockIdx.x*blockDim.x + threadIdx.x)*4;
  int stride = gridDim.x*blockDim.x*4;
  for (; i < n; i += stride){
    float4 v = *(const float4*)(src+i);
    __hip_bfloat16 o[4] = {__float2bfloat16(v.x),__float2bfloat16(v.y),__float2bfloat16(v.z),__float2bfloat16(v.w)};
    *(short4v*)(dst+i) = *(const short4v*)o;
  }
}

// Wq [1024][1024] f32 -> WqT bf16 (dst[h][d] = src[d][h])
__global__ void k_tcvt(const float* __restrict__ src, __hip_bfloat16* __restrict__ dst){
  __shared__ float tile[64][65];
  int i0 = blockIdx.y*64, j0 = blockIdx.x*64;
  int tr = threadIdx.x >> 6, tc = threadIdx.x & 63;
  for (int p=0;p<16;p++){ int r = p*4 + tr; tile[r][tc] = src[(size_t)(i0+r)*1024 + j0+tc]; }
  __syncthreads();
  for (int p=0;p<16;p++){ int r = p*4 + tr; dst[(size_t)(j0+r)*1024 + i0+tc] = __float2bfloat16(tile[tc][r]); }
}

// Wih2[r][c] = W_ih[r][1024+c], r<4096
__global__ void k_extract(const float* __restrict__ src, __hip_bfloat16* __restrict__ dst){
  int i = blockIdx.x*blockDim.x + threadIdx.x;
  int stride = gridDim.x*blockDim.x;
  for (; i < 4096*1024; i += stride){
    int r = i >> 10, c = i & 1023;
    dst[i] = __float2bfloat16(src[((size_t)r << 11) + 1024 + c]);
  }
}

__global__ void k_init(const float* __restrict__ eh, __hip_bfloat16* __restrict__ hg,
                       unsigned* __restrict__ bars){
  int i = blockIdx.x*blockDim.x + threadIdx.x;
  if (i < 16384) hg[i] = __float2bfloat16(eh[i]);
  if (i < 2048) bars[i] = 0u;   // 8KB of counters
}

// gate_const[n] = b_ih[n] + b_hh[n] + emb[SOS]·W_ih[n, 0:1024]
__global__ void k_gconst(const float* __restrict__ emb, const float* __restrict__ Wih,
                         const float* __restrict__ bih, const float* __restrict__ bhh,
                         float* __restrict__ gc){
  int w = threadIdx.x >> 6, lane = threadIdx.x & 63;
  int n = blockIdx.x*4 + w;
  const float* er = emb + 1024;  // SOS = 1
  const float* wr = Wih + (size_t)n*2048;
  float acc = 0.f;
  for (int q=0;q<16;q++){ int k = lane*16+q; acc += er[k]*wr[k]; }
  for (int off=32; off; off>>=1) acc += __shfl_xor(acc, off);
  if (lane==0) gc[n] = acc + bih[n] + bhh[n];
}

// sb[r] = (bq · K[r,:]) / 32
__global__ void k_sb(const __hip_bfloat16* __restrict__ Kb, const float* __restrict__ bq,
                     float* __restrict__ sb){
  int w = threadIdx.x >> 6, lane = threadIdx.x & 63;
  int r = blockIdx.x*4 + w;
  const __hip_bfloat16* kr = Kb + (size_t)r*1024;
  float acc = 0.f;
  for (int q=0;q<16;q++){ int k = lane*16+q; acc += __bfloat162float(kr[k])*bq[k]; }
  for (int off=32; off; off>>=1) acc += __shfl_xor(acc, off);
  if (lane==0) sb[r] = acc * 0.03125f;
}

// V [16*512][1024] -> VT [16][1024][512]
__global__ void k_vtrans(const __hip_bfloat16* __restrict__ V, __hip_bfloat16* __restrict__ VT){
  __shared__ short t[64][65];
  int b = blockIdx.z, s0 = blockIdx.y*64, h0 = blockIdx.x*64;
  int r = threadIdx.x >> 6, c = threadIdx.x & 63;
  const short* vp = (const short*)V + ((size_t)(b*512 + s0))*1024 + h0;
  #pragma unroll
  for (int p=0;p<16;p++) t[p*4+r][c] = vp[(size_t)(p*4+r)*1024 + c];
  __syncthreads();
  short* op = (short*)VT + ((size_t)(b*1024 + h0))*512 + s0;
  #pragma unroll
  for (int p=0;p<16;p++) op[(size_t)(p*4+r)*512 + c] = t[c][p*4+r];
}

// ---------------- GEMM: C = scale*(A @ B^T) + bias ----------------
template<int EPI>
__global__ __launch_bounds__(256) void k_gemm(const __hip_bfloat16* __restrict__ A,
    const __hip_bfloat16* __restrict__ Bm, const float* __restrict__ bias,
    void* __restrict__ Cp, int M, int N, int K, float scale){
  __shared__ __hip_bfloat16 sA[128*40];
  __shared__ __hip_bfloat16 sB[128*40];
  int tid = threadIdx.x;
  int lane = tid & 63, w = tid >> 6;
  int wr = w >> 1, wc = w & 1;
  int m0 = blockIdx.y*128, n0 = blockIdx.x*128;
  int lrow = lane & 15, lk = lane >> 4;
  f32x4 acc[4][4] = {};
  for (int k0 = 0; k0 < K; k0 += 32){
    __syncthreads();
    #pragma unroll
    for (int l0 = 0; l0 < 1024; l0 += 256){
      int l = l0 + tid;
      int half = l >> 9;
      int ch = l & 511;
      int row = ch >> 2, seg = ch & 3;
      const __hip_bfloat16* src = half ? (Bm + (size_t)(n0+row)*K + k0 + seg*8)
                                       : (A  + (size_t)(m0+row)*K + k0 + seg*8);
      __hip_bfloat16* dst = (half ? sB : sA) + row*40 + seg*8;
      *(short8*)dst = *(const short8*)src;
    }
    __syncthreads();
    short8 af[4], bfq[4];
    #pragma unroll
    for (int mi=0;mi<4;mi++) af[mi]  = *(short8*)(sA + (wr*64+mi*16+lrow)*40 + lk*8);
    #pragma unroll
    for (int ni=0;ni<4;ni++) bfq[ni] = *(short8*)(sB + (wc*64+ni*16+lrow)*40 + lk*8);
    #pragma unroll
    for (int mi=0;mi<4;mi++)
      #pragma unroll
      for (int ni=0;ni<4;ni++)
        acc[mi][ni] = __builtin_amdgcn_mfma_f32_16x16x32_bf16(af[mi], bfq[ni], acc[mi][ni], 0,0,0);
  }
  int crow0 = (lane>>4)*4;
  int ccol = lane & 15;
  #pragma unroll
  for (int mi=0;mi<4;mi++)
    #pragma unroll
    for (int ni=0;ni<4;ni++){
      int gn = n0 + wc*64 + ni*16 + ccol;
      float bv = bias ? bias[gn] : 0.0f;
      #pragma unroll
      for (int j=0;j<4;j++){
        int gm = m0 + wr*64 + mi*16 + crow0 + j;
        float v = acc[mi][ni][j]*scale + bv;
        if (EPI==0){
          ((__hip_bfloat16*)Cp)[(size_t)gm*N + gn] = __float2bfloat16(v);
        } else {
          int tt = gm >> 4, bb = gm & 15;
          ((float*)Cp)[(size_t)(bb*128+tt)*N + gn] = v;
        }
      }
    }
}

// ---------------- barrier (monotone counter, generation target) ----------------
DEVI void bar_sync(unsigned* ctr, unsigned target){
  __syncthreads();
  if (threadIdx.x == 0){
    __threadfence();
    __hip_atomic_fetch_add(ctr, 1u, __ATOMIC_RELAXED, __HIP_MEMORY_SCOPE_AGENT);
    while (__hip_atomic_load(ctr, __ATOMIC_RELAXED, __HIP_MEMORY_SCOPE_AGENT) < target)
      __builtin_amdgcn_s_sleep(2);
    __threadfence();
  }
  __syncthreads();
}

// ---------------- persistent decoder: 4 independent groups of 64 blocks ----------------
// blk: xcd = blk&7, slot = blk>>3. grp = xcd>>1 (4 batches), half = xcd&1.
// bloc = half*2 + (slot>>4), chunk = slot&15  -> attention: batch b = grp*4+bloc,
//   positions [chunk*32, +32), ctx dims [chunk*64, +64).
// gates: jblk = half*32+slot (0..63), j0 = jblk*16: 4 gate types x 16 cols, K=2048
//   (wave w: K-slice (w&1)*512 of h-part (w<2) or ctx-part (w>=2)). M=4 batches.
__global__ __launch_bounds__(256, 1) void k_decode(
    const __hip_bfloat16* __restrict__ KQ, const __hip_bfloat16* __restrict__ VT,
    const float* __restrict__ sb, const __hip_bfloat16* __restrict__ Whh,
    const __hip_bfloat16* __restrict__ Wih2, const float* __restrict__ gconst,
    const float* __restrict__ ec,
    __hip_bfloat16* __restrict__ hglob, float* __restrict__ eg,
    __hip_bfloat16* __restrict__ ctxn, __hip_bfloat16* __restrict__ hall,
    float* __restrict__ outH, float* __restrict__ outC, unsigned* __restrict__ bars)
{
  __shared__ __attribute__((aligned(16))) __hip_bfloat16 h4L[4][1032]; // 4 batches x 1024 (+8 pad)
  __shared__ __attribute__((aligned(16))) float eL[528];
  __shared__ __attribute__((aligned(16))) float sPf[1024];             // [w][t][col] f32x4 over batches
  __shared__ __attribute__((aligned(16))) __hip_bfloat16 sCtx[64];
  __shared__ float sSb[32];
  __shared__ float sGc[64];
  __shared__ float sRed[4];

  const int tid = threadIdx.x;
  const int lane = tid & 63, wv = tid >> 6;
  const int l16 = lane & 15, lhi = lane >> 4;
  const int blk = blockIdx.x;
  const int xcd = blk & 7, slot = blk >> 3;
  const int grp = xcd >> 1, half = xcd & 1;
  const int bloc = half*2 + (slot >> 4);
  const int chunk = slot & 15;
  const int g4 = grp*4;
  const int b = g4 + bloc;
  const int j0 = (half*32 + slot) * 16;

  unsigned* gctr = bars + grp*64;
  unsigned* bctr = bars + 1024 + b*64;

  // gate-weight fragments, register-resident: 4 Ntiles x 16 ktiles (K-slice 512/wave)
  short8 wfrag[64];
  {
    const __hip_bfloat16* wsrc = (wv < 2) ? Whh : Wih2;
    const int koff = (wv & 1) * 512;
    #pragma unroll
    for (int tt = 0; tt < 4; tt++)
      #pragma unroll
      for (int kt = 0; kt < 16; kt++)
        wfrag[tt*16+kt] = *(const short8*)(wsrc + (size_t)(tt*1024 + j0 + l16)*1024 + koff + kt*32 + lhi*8);
  }
  if (tid < 32) sSb[tid] = sb[b*512 + chunk*32 + tid];
  if (tid < 64) sGc[(tid>>4)*16 + (tid&15)] = gconst[(tid>>4)*1024 + j0 + (tid&15)];
  float creg = 0.f;
  if (tid < 64) creg = ec[(size_t)(g4 + (tid>>4))*1024 + j0 + (tid&15)];

  const __hip_bfloat16* kqBlk = KQ + ((size_t)(b*512 + chunk*32))*1024;
  const int ar = (l16 < 4) ? l16 : 3;
  const short8 zfrag = {};
  f32x4 gacc[4] = {};
  unsigned tb = 0, tg = 0;

  for (int st = 0; st < 128; ++st){
    // ---- phase A: stage h (4 batches), scores -> e, h-part gate MFMA ----
    #pragma unroll
    for (int p = 0; p < 2; p++){
      int m = p*256 + tid;              // 0..511 = 4 rows x 128 short8 segs
      int r = m >> 7, seg = m & 127;
      *(short8*)&h4L[r][seg*8] = *(const short8*)(hglob + (size_t)(g4 + r)*1024 + seg*8);
    }
    __syncthreads();
    {
      int row = tid >> 3, kx = tid & 7;
      const __hip_bfloat16* kp = kqBlk + (size_t)row*1024 + kx*8;
      float acc = 0.f;
      #pragma unroll
      for (int q = 0; q < 16; q++){
        short8 kv = *(const short8*)(kp + q*64);
        short8 hv = *(const short8*)&h4L[bloc][kx*8 + q*64];
        #pragma unroll
        for (int e2 = 0; e2 < 8; e2++) acc += bf2f(hv[e2]) * bf2f(kv[e2]);
      }
      acc += __shfl_xor(acc, 1); acc += __shfl_xor(acc, 2); acc += __shfl_xor(acc, 4);
      if (kx == 0) eg[b*512 + chunk*32 + row] = expf(acc + sSb[row]);
    }
    if (wv < 2){
      const int ko = (wv & 1) * 512;
      #pragma unroll
      for (int kt = 0; kt < 16; kt++){
        short8 a = *(const short8*)&h4L[ar][ko + kt*32 + lhi*8];
        a = (l16 < 4) ? a : zfrag;
        #pragma unroll
        for (int tt = 0; tt < 4; tt++)
          gacc[tt] = __builtin_amdgcn_mfma_f32_16x16x32_bf16(a, wfrag[tt*16+kt], gacc[tt], 0,0,0);
      }
    }
    tb += 16; bar_sync(bctr, tb);

    // ---- phase B: full e[b] -> L, normalized ctx slice (own 64 dims) ----
    {
      float ep0 = eg[b*512 + tid];
      int s1 = tid + 256;
      float ep1 = eg[b*512 + s1];
      eL[tid + ((tid>>7)<<2)] = ep0;
      eL[s1 + ((s1>>7)<<2)] = ep1;
      float lp = ep0 + ep1;
      for (int off=32; off; off>>=1) lp += __shfl_xor(lp, off);
      if (lane == 0) sRed[wv] = lp;
    }
    __syncthreads();
    {
      float Linv = 1.0f/(sRed[0]+sRed[1]+sRed[2]+sRed[3]);
      int hloc = tid >> 2, sc = (tid & 3)*128;
      const __hip_bfloat16* vp = VT + ((size_t)(b*1024 + chunk*64 + hloc))*512 + sc;
      const float* ep = eL + sc + ((sc>>7)<<2);
      float a = 0.f;
      #pragma unroll
      for (int q = 0; q < 16; q++){
        short8 vv = *(const short8*)(vp + q*8);
        float4 e0 = *(const float4*)(ep + q*8);
        float4 e1 = *(const float4*)(ep + q*8 + 4);
        a += e0.x*bf2f(vv[0]) + e0.y*bf2f(vv[1]) + e0.z*bf2f(vv[2]) + e0.w*bf2f(vv[3]);
        a += e1.x*bf2f(vv[4]) + e1.y*bf2f(vv[5]) + e1.z*bf2f(vv[6]) + e1.w*bf2f(vv[7]);
      }
      a += __shfl_xor(a, 1); a += __shfl_xor(a, 2);
      if ((tid & 3) == 0) sCtx[hloc] = __float2bfloat16(a * Linv);
    }
    __syncthreads();
    if (tid < 8) *(short8*)(ctxn + (size_t)b*1024 + chunk*64 + tid*8) = *(const short8*)(sCtx + tid*8);
    tg += 64; bar_sync(gctr, tg);

    // ---- phase C: stage ctx (4 batches), ctx-part gate MFMA, gates, LSTM ----
    #pragma unroll
    for (int p = 0; p < 2; p++){
      int m = p*256 + tid;
      int r = m >> 7, seg = m & 127;
      *(short8*)&h4L[r][seg*8] = *(const short8*)(ctxn + (size_t)(g4 + r)*1024 + seg*8);
    }
    __syncthreads();
    if (wv >= 2){
      const int ko = (wv & 1) * 512;
      #pragma unroll
      for (int kt = 0; kt < 16; kt++){
        short8 a = *(const short8*)&h4L[ar][ko + kt*32 + lhi*8];
        a = (l16 < 4) ? a : zfrag;
        #pragma unroll
        for (int tt = 0; tt < 4; tt++)
          gacc[tt] = __builtin_amdgcn_mfma_f32_16x16x32_bf16(a, wfrag[tt*16+kt], gacc[tt], 0,0,0);
      }
    }
    if (lhi == 0){
      #pragma unroll
      for (int tt = 0; tt < 4; tt++)
        *(f32x4*)&sPf[(wv*64 + tt*16 + l16)*4] = gacc[tt];
    }
    #pragma unroll
    for (int tt = 0; tt < 4; tt++) gacc[tt] = (f32x4){0.f,0.f,0.f,0.f};
    __syncthreads();
    if (tid < 64){
      int bb = tid >> 4, jj = tid & 15;
      float gv[4];
      #pragma unroll
      for (int tt = 0; tt < 4; tt++){
        float s = sGc[tt*16 + jj];
        #pragma unroll
        for (int w2 = 0; w2 < 4; w2++) s += sPf[(w2*64 + tt*16 + jj)*4 + bb];
        gv[tt] = s;
      }
      float si = 1.f/(1.f+expf(-gv[0]));
      float sf = 1.f/(1.f+expf(-gv[1]));
      float so = 1.f/(1.f+expf(-gv[3]));
      float c2 = sf*creg + si*tanhf(gv[2]);
      float h2 = so*tanhf(c2);
      creg = c2;
      int gb = g4 + bb;
      __hip_bfloat16 hbv = __float2bfloat16(h2);
      hglob[(size_t)gb*1024 + j0 + jj] = hbv;
      hall[((size_t)(st*16 + gb))*1024 + j0 + jj] = hbv;
      if (st == 127){ outH[gb*1024 + j0 + jj] = h2; outC[gb*1024 + j0 + jj] = c2; }
    }
    tg += 64; bar_sync(gctr, tg);
  }
}

// ---------------- in-place log-softmax over rows of 32000 ----------------
__global__ __launch_bounds__(256) void k_logsm(float* __restrict__ out){
  int row = blockIdx.x;
  float* p = out + (size_t)row*32000;
  int tid = threadIdx.x;
  __shared__ float red[4];
  float s = 0.f;
  for (int i = tid*4; i < 32000; i += 1024){
    float4 v = *(float4*)(p+i);
    s += __expf(v.x)+__expf(v.y)+__expf(v.z)+__expf(v.w);
  }
  for (int off=32; off; off>>=1) s += __shfl_xor(s, off);
  if ((tid&63)==0) red[tid>>6] = s;
  __syncthreads();
  float L = logf(red[0]+red[1]+red[2]+red[3]);
  for (int i = tid*4; i < 32000; i += 1024){
    float4 v = *(float4*)(p+i);
    v.x-=L; v.y-=L; v.z-=L; v.w-=L;
    *(float4*)(p+i) = v;
  }
}

extern "C" void kernel_launch(void* const* d_in, const int* in_sizes, int n_in,
                              void* d_out, int out_size, void* d_ws, size_t ws_size,
                              hipStream_t stream){
  const float* enc = (const float*)d_in[0];
  const float* eh  = (const float*)d_in[1];
  const float* ec  = (const float*)d_in[2];
  const float* emb = (const float*)d_in[3];
  const float* Wq  = (const float*)d_in[4];
  const float* bq  = (const float*)d_in[5];
  const float* Wk  = (const float*)d_in[6];
  const float* bk  = (const float*)d_in[7];
  const float* Wv  = (const float*)d_in[8];
  const float* bv  = (const float*)d_in[9];
  const float* Wih = (const float*)d_in[10];
  const float* bih = (const float*)d_in[11];
  const float* Whh = (const float*)d_in[12];
  const float* bhh = (const float*)d_in[13];
  const float* Wo  = (const float*)d_in[14];
  const float* bo  = (const float*)d_in[15];

  char* ws = (char*)d_ws;
  __hip_bfloat16* encbf = (__hip_bfloat16*)(ws + o_encbf);
  __hip_bfloat16* kbf   = (__hip_bfloat16*)(ws + o_kbf);
  __hip_bfloat16* wkbf  = (__hip_bfloat16*)(ws + o_wkbf);
  __hip_bfloat16* wvbf  = (__hip_bfloat16*)(ws + o_wvbf);
  __hip_bfloat16* wqtbf = (__hip_bfloat16*)(ws + o_wqtbf);
  __hip_bfloat16* vt    = (__hip_bfloat16*)(ws + o_vt);
  __hip_bfloat16* woutbf= (__hip_bfloat16*)(ws + o_wout);
  __hip_bfloat16* kq    = (__hip_bfloat16*)(ws + o_kq);
  __hip_bfloat16* vbf   = (__hip_bfloat16*)(ws + o_vbf);
  __hip_bfloat16* wih2  = (__hip_bfloat16*)(ws + o_wih2);
  __hip_bfloat16* whhbf = (__hip_bfloat16*)(ws + o_whh);
  __hip_bfloat16* hall  = (__hip_bfloat16*)(ws + o_hall);
  float* gconst = (float*)(ws + o_gconst);
  float* sbp    = (float*)(ws + o_sb);
  __hip_bfloat16* hglob = (__hip_bfloat16*)(ws + o_hg);
  __hip_bfloat16* ctxn  = (__hip_bfloat16*)(ws + o_ctxn);
  float* eg     = (float*)(ws + o_eg);
  unsigned* bars= (unsigned*)(ws + o_bar);
  float* outP   = (float*)d_out;
  float* outH   = outP + 65536000;
  float* outC   = outH + 16384;

  // ---- precompute ----
  k_convert<<<1024,256,0,stream>>>(enc, encbf, 8388608);
  k_convert<<<256,256,0,stream>>>(Wk, wkbf, 1048576);
  k_convert<<<256,256,0,stream>>>(Wv, wvbf, 1048576);
  k_tcvt<<<dim3(16,16),256,0,stream>>>(Wq, wqtbf);
  k_gemm<0><<<dim3(8,64),256,0,stream>>>(encbf, wkbf, bk, kbf, 8192,1024,1024, 1.f);
  k_gemm<0><<<dim3(8,64),256,0,stream>>>(encbf, wvbf, bv, vbf, 8192,1024,1024, 1.f);
  k_gemm<0><<<dim3(8,64),256,0,stream>>>(kbf, wqtbf, (const float*)nullptr, kq, 8192,1024,1024, 0.03125f);
  k_vtrans<<<dim3(16,8,16),256,0,stream>>>(vbf, vt);
  k_sb<<<2048,256,0,stream>>>(kbf, bq, sbp);
  k_extract<<<1024,256,0,stream>>>(Wih, wih2);
  k_convert<<<1024,256,0,stream>>>(Whh, whhbf, 4194304);
  k_gconst<<<1024,256,0,stream>>>(emb, Wih, bih, bhh, gconst);
  k_init<<<64,256,0,stream>>>(eh, hglob, bars);

  // ---- recurrence: persistent kernel, 4 independent groups ----
  {
    const __hip_bfloat16* a_kq = kq; const __hip_bfloat16* a_vt = vt;
    const float* a_sb = sbp; const __hip_bfloat16* a_whh = whhbf;
    const __hip_bfloat16* a_wih = wih2; const float* a_gc = gconst;
    const float* a_ec = ec;
    __hip_bfloat16* a_hg = hglob; float* a_eg = eg;
    __hip_bfloat16* a_cx = ctxn; __hip_bfloat16* a_ha = hall;
    float* a_oh = outH; float* a_oc = outC; unsigned* a_bar = bars;
    void* args[] = { &a_kq, &a_vt, &a_sb, &a_whh, &a_wih, &a_gc, &a_ec,
                     &a_hg, &a_eg, &a_cx, &a_ha, &a_oh, &a_oc, &a_bar };
    hipError_t err = hipLaunchCooperativeKernel((void*)k_decode, dim3(256), dim3(256),
                                                args, 0u, stream);
    if (err != hipSuccess){
      k_decode<<<256,256,0,stream>>>(kq, vt, sbp, whhbf, wih2, gconst, ec,
                                     hglob, eg, ctxn, hall, outH, outC, bars);
    }
  }

  // ---- logits + log-softmax ----
  k_convert<<<2048,256,0,stream>>>(Wo, woutbf, 32768000);
  k_gemm<1><<<dim3(250,16),256,0,stream>>>(hall, woutbf, bo, d_out, 2048,32000,1024, 1.f);
  k_logsm<<<2048,256,0,stream>>>(outP);
}

// Round 5
// 2820.983 us; speedup vs baseline: 2.6426x; 2.0483x over previous
//
#include <hip/hip_runtime.h>
#include <hip/hip_bf16.h>
#include <math.h>

typedef short short8 __attribute__((ext_vector_type(8)));
typedef short short4v __attribute__((ext_vector_type(4)));
typedef float f32x4 __attribute__((ext_vector_type(4)));
typedef unsigned long long u64;

#define DEVI __device__ __forceinline__

DEVI float bf2f(short s){ union{unsigned u; float f;} x; x.u = ((unsigned)(unsigned short)s) << 16; return x.f; }

// system-scope relaxed (sc0 sc1: bypass L1/L2, coherent point) payload ops — NO fences
DEVI void st_u64v(u64* p, u64 v){ __hip_atomic_store(p, v, __ATOMIC_RELAXED, __HIP_MEMORY_SCOPE_SYSTEM); }
DEVI u64  ld_u64v(const u64* p){ return __hip_atomic_load(p, __ATOMIC_RELAXED, __HIP_MEMORY_SCOPE_SYSTEM); }
DEVI void st_f32v(float* p, float v){ __hip_atomic_store(p, v, __ATOMIC_RELAXED, __HIP_MEMORY_SCOPE_SYSTEM); }
DEVI float ld_f32v(const float* p){ return __hip_atomic_load(p, __ATOMIC_RELAXED, __HIP_MEMORY_SCOPE_SYSTEM); }
DEVI void st_u16v(unsigned short* p, unsigned short v){ __hip_atomic_store(p, v, __ATOMIC_RELAXED, __HIP_MEMORY_SCOPE_SYSTEM); }

// V=32000 H=1024 S=512 B=16 T=128, SOS=1
// ws layout (bytes)
constexpr size_t o_wout   = 0;                          // bf16 [32000*1024]
constexpr size_t o_encbf  = 0;                          // overlay (dead before wout used)
constexpr size_t o_kbf    = 16777216;                   // overlay
constexpr size_t o_wkbf   = 33554432;                   // overlay
constexpr size_t o_wvbf   = 35651584;                   // overlay
constexpr size_t o_wqtbf  = 37748736;                   // overlay
constexpr size_t o_vt     = 41943040;                   // overlay: bf16 VT [16][1024][512]
constexpr size_t o_kq     = 65536000;                   // bf16 [8192*1024]
constexpr size_t o_vbf    = o_kq    + 16777216;         // bf16 [8192*1024]
constexpr size_t o_wih2   = o_vbf   + 16777216;         // bf16 [4096*1024]
constexpr size_t o_whh    = o_wih2  + 8388608;          // bf16 [4096*1024]
constexpr size_t o_hall   = o_whh   + 8388608;          // bf16 [2048*1024]
constexpr size_t o_gconst = o_hall  + 4194304;          // f32 [4096]
constexpr size_t o_sb     = o_gconst+ 16384;            // f32 [8192]
constexpr size_t o_hg     = o_sb    + 32768;            // bf16 [16*1024] current h
constexpr size_t o_ctxn   = o_hg    + 32768;            // bf16 [16*1024] normalized ctx
constexpr size_t o_eg     = o_ctxn  + 32768;            // f32 [16*512] exp scores
constexpr size_t o_bar    = o_eg    + 32768;            // u32 counters

// ---------------- elementwise converts ----------------
__global__ void k_convert(const float* __restrict__ src, __hip_bfloat16* __restrict__ dst, int n){
  int i = (blockIdx.x*blockDim.x + threadIdx.x)*4;
  int stride = gridDim.x*blockDim.x*4;
  for (; i < n; i += stride){
    float4 v = *(const float4*)(src+i);
    __hip_bfloat16 o[4] = {__float2bfloat16(v.x),__float2bfloat16(v.y),__float2bfloat16(v.z),__float2bfloat16(v.w)};
    *(short4v*)(dst+i) = *(const short4v*)o;
  }
}

// Wq [1024][1024] f32 -> WqT bf16 (dst[h][d] = src[d][h])
__global__ void k_tcvt(const float* __restrict__ src, __hip_bfloat16* __restrict__ dst){
  __shared__ float tile[64][65];
  int i0 = blockIdx.y*64, j0 = blockIdx.x*64;
  int tr = threadIdx.x >> 6, tc = threadIdx.x & 63;
  for (int p=0;p<16;p++){ int r = p*4 + tr; tile[r][tc] = src[(size_t)(i0+r)*1024 + j0+tc]; }
  __syncthreads();
  for (int p=0;p<16;p++){ int r = p*4 + tr; dst[(size_t)(j0+r)*1024 + i0+tc] = __float2bfloat16(tile[tc][r]); }
}

// Wih2[r][c] = W_ih[r][1024+c], r<4096
__global__ void k_extract(const float* __restrict__ src, __hip_bfloat16* __restrict__ dst){
  int i = blockIdx.x*blockDim.x + threadIdx.x;
  int stride = gridDim.x*blockDim.x;
  for (; i < 4096*1024; i += stride){
    int r = i >> 10, c = i & 1023;
    dst[i] = __float2bfloat16(src[((size_t)r << 11) + 1024 + c]);
  }
}

__global__ void k_init(const float* __restrict__ eh, __hip_bfloat16* __restrict__ hg,
                       unsigned* __restrict__ bars){
  int i = blockIdx.x*blockDim.x + threadIdx.x;
  if (i < 16384) hg[i] = __float2bfloat16(eh[i]);
  if (i < 2048) bars[i] = 0u;
}

// gate_const[n] = b_ih[n] + b_hh[n] + emb[SOS]·W_ih[n, 0:1024]
__global__ void k_gconst(const float* __restrict__ emb, const float* __restrict__ Wih,
                         const float* __restrict__ bih, const float* __restrict__ bhh,
                         float* __restrict__ gc){
  int w = threadIdx.x >> 6, lane = threadIdx.x & 63;
  int n = blockIdx.x*4 + w;
  const float* er = emb + 1024;  // SOS = 1
  const float* wr = Wih + (size_t)n*2048;
  float acc = 0.f;
  for (int q=0;q<16;q++){ int k = lane*16+q; acc += er[k]*wr[k]; }
  for (int off=32; off; off>>=1) acc += __shfl_xor(acc, off);
  if (lane==0) gc[n] = acc + bih[n] + bhh[n];
}

// sb[r] = (bq · K[r,:]) / 32
__global__ void k_sb(const __hip_bfloat16* __restrict__ Kb, const float* __restrict__ bq,
                     float* __restrict__ sb){
  int w = threadIdx.x >> 6, lane = threadIdx.x & 63;
  int r = blockIdx.x*4 + w;
  const __hip_bfloat16* kr = Kb + (size_t)r*1024;
  float acc = 0.f;
  for (int q=0;q<16;q++){ int k = lane*16+q; acc += __bfloat162float(kr[k])*bq[k]; }
  for (int off=32; off; off>>=1) acc += __shfl_xor(acc, off);
  if (lane==0) sb[r] = acc * 0.03125f;
}

// V [16*512][1024] -> VT [16][1024][512]
__global__ void k_vtrans(const __hip_bfloat16* __restrict__ V, __hip_bfloat16* __restrict__ VT){
  __shared__ short t[64][65];
  int b = blockIdx.z, s0 = blockIdx.y*64, h0 = blockIdx.x*64;
  int r = threadIdx.x >> 6, c = threadIdx.x & 63;
  const short* vp = (const short*)V + ((size_t)(b*512 + s0))*1024 + h0;
  #pragma unroll
  for (int p=0;p<16;p++) t[p*4+r][c] = vp[(size_t)(p*4+r)*1024 + c];
  __syncthreads();
  short* op = (short*)VT + ((size_t)(b*1024 + h0))*512 + s0;
  #pragma unroll
  for (int p=0;p<16;p++) op[(size_t)(p*4+r)*512 + c] = t[c][p*4+r];
}

// ---------------- GEMM: C = scale*(A @ B^T) + bias ----------------
template<int EPI>
__global__ __launch_bounds__(256) void k_gemm(const __hip_bfloat16* __restrict__ A,
    const __hip_bfloat16* __restrict__ Bm, const float* __restrict__ bias,
    void* __restrict__ Cp, int M, int N, int K, float scale){
  __shared__ __hip_bfloat16 sA[128*40];
  __shared__ __hip_bfloat16 sB[128*40];
  int tid = threadIdx.x;
  int lane = tid & 63, w = tid >> 6;
  int wr = w >> 1, wc = w & 1;
  int m0 = blockIdx.y*128, n0 = blockIdx.x*128;
  int lrow = lane & 15, lk = lane >> 4;
  f32x4 acc[4][4] = {};
  for (int k0 = 0; k0 < K; k0 += 32){
    __syncthreads();
    #pragma unroll
    for (int l0 = 0; l0 < 1024; l0 += 256){
      int l = l0 + tid;
      int half = l >> 9;
      int ch = l & 511;
      int row = ch >> 2, seg = ch & 3;
      const __hip_bfloat16* src = half ? (Bm + (size_t)(n0+row)*K + k0 + seg*8)
                                       : (A  + (size_t)(m0+row)*K + k0 + seg*8);
      __hip_bfloat16* dst = (half ? sB : sA) + row*40 + seg*8;
      *(short8*)dst = *(const short8*)src;
    }
    __syncthreads();
    short8 af[4], bfq[4];
    #pragma unroll
    for (int mi=0;mi<4;mi++) af[mi]  = *(short8*)(sA + (wr*64+mi*16+lrow)*40 + lk*8);
    #pragma unroll
    for (int ni=0;ni<4;ni++) bfq[ni] = *(short8*)(sB + (wc*64+ni*16+lrow)*40 + lk*8);
    #pragma unroll
    for (int mi=0;mi<4;mi++)
      #pragma unroll
      for (int ni=0;ni<4;ni++)
        acc[mi][ni] = __builtin_amdgcn_mfma_f32_16x16x32_bf16(af[mi], bfq[ni], acc[mi][ni], 0,0,0);
  }
  int crow0 = (lane>>4)*4;
  int ccol = lane & 15;
  #pragma unroll
  for (int mi=0;mi<4;mi++)
    #pragma unroll
    for (int ni=0;ni<4;ni++){
      int gn = n0 + wc*64 + ni*16 + ccol;
      float bv = bias ? bias[gn] : 0.0f;
      #pragma unroll
      for (int j=0;j<4;j++){
        int gm = m0 + wr*64 + mi*16 + crow0 + j;
        float v = acc[mi][ni][j]*scale + bv;
        if (EPI==0){
          ((__hip_bfloat16*)Cp)[(size_t)gm*N + gn] = __float2bfloat16(v);
        } else {
          int tt = gm >> 4, bb = gm & 15;
          ((float*)Cp)[(size_t)(bb*128+tt)*N + gn] = v;
        }
      }
    }
}

// ---------------- fence-free barrier (monotone counter, relaxed atomics) ----------------
// Every thread drains its own vmcnt before s_barrier, so by barrier-exit all
// payload (sc0sc1 write-through) stores are at the coherent point. The counter
// add needs no release fence; pollers need no acquire fence (payload reads
// also bypass L1/L2). -> NO buffer_wbl2 / buffer_inv: L2 stays resident.
DEVI void bar_sync(unsigned* ctr, unsigned target){
  __builtin_amdgcn_s_waitcnt(0);
  __syncthreads();
  if (threadIdx.x == 0){
    __hip_atomic_fetch_add(ctr, 1u, __ATOMIC_RELAXED, __HIP_MEMORY_SCOPE_SYSTEM);
    while (__hip_atomic_load(ctr, __ATOMIC_RELAXED, __HIP_MEMORY_SCOPE_SYSTEM) < target)
      __builtin_amdgcn_s_sleep(1);
  }
  __syncthreads();
}

// ---------------- persistent decoder: 4 independent groups of 64 blocks ----------------
__global__ __launch_bounds__(256, 1) void k_decode(
    const __hip_bfloat16* __restrict__ KQ, const __hip_bfloat16* __restrict__ VT,
    const float* __restrict__ sb, const __hip_bfloat16* __restrict__ Whh,
    const __hip_bfloat16* __restrict__ Wih2, const float* __restrict__ gconst,
    const float* __restrict__ ec,
    __hip_bfloat16* __restrict__ hglob, float* __restrict__ eg,
    __hip_bfloat16* __restrict__ ctxn, __hip_bfloat16* __restrict__ hall,
    float* __restrict__ outH, float* __restrict__ outC, unsigned* __restrict__ bars)
{
  __shared__ __attribute__((aligned(16))) __hip_bfloat16 h4L[4][1032];
  __shared__ __attribute__((aligned(16))) float eL[528];
  __shared__ __attribute__((aligned(16))) float sPf[1024];
  __shared__ __attribute__((aligned(16))) __hip_bfloat16 sCtx[64];
  __shared__ float sSb[32];
  __shared__ float sGc[64];
  __shared__ float sRed[4];

  const int tid = threadIdx.x;
  const int lane = tid & 63, wv = tid >> 6;
  const int l16 = lane & 15, lhi = lane >> 4;
  const int blk = blockIdx.x;
  const int xcd = blk & 7, slot = blk >> 3;
  const int grp = xcd >> 1, half = xcd & 1;
  const int bloc = half*2 + (slot >> 4);
  const int chunk = slot & 15;
  const int g4 = grp*4;
  const int b = g4 + bloc;
  const int j0 = (half*32 + slot) * 16;

  unsigned* gctr = bars + grp*64;
  unsigned* bctr = bars + 1024 + b*64;

  // gate-weight fragments, register-resident: 4 Ntiles x 16 ktiles (K-slice 512/wave)
  short8 wfrag[64];
  {
    const __hip_bfloat16* wsrc = (wv < 2) ? Whh : Wih2;
    const int koff = (wv & 1) * 512;
    #pragma unroll
    for (int tt = 0; tt < 4; tt++)
      #pragma unroll
      for (int kt = 0; kt < 16; kt++)
        wfrag[tt*16+kt] = *(const short8*)(wsrc + (size_t)(tt*1024 + j0 + l16)*1024 + koff + kt*32 + lhi*8);
  }
  if (tid < 32) sSb[tid] = sb[b*512 + chunk*32 + tid];
  if (tid < 64) sGc[(tid>>4)*16 + (tid&15)] = gconst[(tid>>4)*1024 + j0 + (tid&15)];
  float creg = 0.f;
  if (tid < 64) creg = ec[(size_t)(g4 + (tid>>4))*1024 + j0 + (tid&15)];

  const __hip_bfloat16* kqBlk = KQ + ((size_t)(b*512 + chunk*32))*1024;
  const int ar = (l16 < 4) ? l16 : 3;
  const short8 zfrag = {};
  f32x4 gacc[4] = {};
  unsigned tb = 0, tg = 0;

  for (int st = 0; st < 128; ++st){
    // ---- phase A: stage h (4 batches, bypass loads), scores -> e, h-part gate MFMA ----
    #pragma unroll
    for (int p = 0; p < 4; p++){
      int m = p*256 + tid;               // 0..1023 = 4 rows x 256 u64 segs
      int r = m >> 8, seg = m & 255;
      u64 v = ld_u64v((const u64*)(hglob + (size_t)(g4 + r)*1024) + seg);
      *(u64*)&h4L[r][seg*4] = v;
    }
    __syncthreads();
    {
      int row = tid >> 3, kx = tid & 7;
      const __hip_bfloat16* kp = kqBlk + (size_t)row*1024 + kx*8;
      float acc = 0.f;
      #pragma unroll
      for (int q = 0; q < 16; q++){
        short8 kv = *(const short8*)(kp + q*64);
        short8 hv = *(const short8*)&h4L[bloc][kx*8 + q*64];
        #pragma unroll
        for (int e2 = 0; e2 < 8; e2++) acc += bf2f(hv[e2]) * bf2f(kv[e2]);
      }
      acc += __shfl_xor(acc, 1); acc += __shfl_xor(acc, 2); acc += __shfl_xor(acc, 4);
      if (kx == 0) st_f32v(&eg[b*512 + chunk*32 + row], expf(acc + sSb[row]));
    }
    if (wv < 2){
      const int ko = (wv & 1) * 512;
      #pragma unroll
      for (int kt = 0; kt < 16; kt++){
        short8 a = *(const short8*)&h4L[ar][ko + kt*32 + lhi*8];
        a = (l16 < 4) ? a : zfrag;
        #pragma unroll
        for (int tt = 0; tt < 4; tt++)
          gacc[tt] = __builtin_amdgcn_mfma_f32_16x16x32_bf16(a, wfrag[tt*16+kt], gacc[tt], 0,0,0);
      }
    }
    tb += 16; bar_sync(bctr, tb);

    // ---- phase B: full e[b] -> L, normalized ctx slice (own 64 dims) ----
    {
      float ep0 = ld_f32v(&eg[b*512 + tid]);
      int s1 = tid + 256;
      float ep1 = ld_f32v(&eg[b*512 + s1]);
      eL[tid + ((tid>>7)<<2)] = ep0;
      eL[s1 + ((s1>>7)<<2)] = ep1;
      float lp = ep0 + ep1;
      for (int off=32; off; off>>=1) lp += __shfl_xor(lp, off);
      if (lane == 0) sRed[wv] = lp;
    }
    __syncthreads();
    {
      float Linv = 1.0f/(sRed[0]+sRed[1]+sRed[2]+sRed[3]);
      int hloc = tid >> 2, sc = (tid & 3)*128;
      const __hip_bfloat16* vp = VT + ((size_t)(b*1024 + chunk*64 + hloc))*512 + sc;
      const float* ep = eL + sc + ((sc>>7)<<2);
      float a = 0.f;
      #pragma unroll
      for (int q = 0; q < 16; q++){
        short8 vv = *(const short8*)(vp + q*8);
        float4 e0 = *(const float4*)(ep + q*8);
        float4 e1 = *(const float4*)(ep + q*8 + 4);
        a += e0.x*bf2f(vv[0]) + e0.y*bf2f(vv[1]) + e0.z*bf2f(vv[2]) + e0.w*bf2f(vv[3]);
        a += e1.x*bf2f(vv[4]) + e1.y*bf2f(vv[5]) + e1.z*bf2f(vv[6]) + e1.w*bf2f(vv[7]);
      }
      a += __shfl_xor(a, 1); a += __shfl_xor(a, 2);
      if ((tid & 3) == 0) sCtx[hloc] = __float2bfloat16(a * Linv);
    }
    __syncthreads();
    if (tid < 16) st_u64v((u64*)(ctxn + (size_t)b*1024 + chunk*64) + tid, ((const u64*)sCtx)[tid]);
    tg += 64; bar_sync(gctr, tg);

    // ---- phase C: stage ctx (bypass loads), ctx-part gate MFMA, gates, LSTM ----
    #pragma unroll
    for (int p = 0; p < 4; p++){
      int m = p*256 + tid;
      int r = m >> 8, seg = m & 255;
      u64 v = ld_u64v((const u64*)(ctxn + (size_t)(g4 + r)*1024) + seg);
      *(u64*)&h4L[r][seg*4] = v;
    }
    __syncthreads();
    if (wv >= 2){
      const int ko = (wv & 1) * 512;
      #pragma unroll
      for (int kt = 0; kt < 16; kt++){
        short8 a = *(const short8*)&h4L[ar][ko + kt*32 + lhi*8];
        a = (l16 < 4) ? a : zfrag;
        #pragma unroll
        for (int tt = 0; tt < 4; tt++)
          gacc[tt] = __builtin_amdgcn_mfma_f32_16x16x32_bf16(a, wfrag[tt*16+kt], gacc[tt], 0,0,0);
      }
    }
    if (lhi == 0){
      #pragma unroll
      for (int tt = 0; tt < 4; tt++)
        *(f32x4*)&sPf[(wv*64 + tt*16 + l16)*4] = gacc[tt];
    }
    #pragma unroll
    for (int tt = 0; tt < 4; tt++) gacc[tt] = (f32x4){0.f,0.f,0.f,0.f};
    __syncthreads();
    if (tid < 64){
      int bb = tid >> 4, jj = tid & 15;
      float gv[4];
      #pragma unroll
      for (int tt = 0; tt < 4; tt++){
        float s = sGc[tt*16 + jj];
        #pragma unroll
        for (int w2 = 0; w2 < 4; w2++) s += sPf[(w2*64 + tt*16 + jj)*4 + bb];
        gv[tt] = s;
      }
      float si = 1.f/(1.f+expf(-gv[0]));
      float sf = 1.f/(1.f+expf(-gv[1]));
      float so = 1.f/(1.f+expf(-gv[3]));
      float c2 = sf*creg + si*tanhf(gv[2]);
      float h2 = so*tanhf(c2);
      creg = c2;
      int gb = g4 + bb;
      __hip_bfloat16 hbv = __float2bfloat16(h2);
      unsigned short hbits; __builtin_memcpy(&hbits, &hbv, 2);
      st_u16v((unsigned short*)hglob + (size_t)gb*1024 + j0 + jj, hbits);
      hall[((size_t)(st*16 + gb))*1024 + j0 + jj] = hbv;
      if (st == 127){ outH[gb*1024 + j0 + jj] = h2; outC[gb*1024 + j0 + jj] = c2; }
    }
    tg += 64; bar_sync(gctr, tg);
  }
}

// ---------------- in-place log-softmax over rows of 32000 ----------------
__global__ __launch_bounds__(256) void k_logsm(float* __restrict__ out){
  int row = blockIdx.x;
  float* p = out + (size_t)row*32000;
  int tid = threadIdx.x;
  __shared__ float red[4];
  float s = 0.f;
  for (int i = tid*4; i < 32000; i += 1024){
    float4 v = *(float4*)(p+i);
    s += __expf(v.x)+__expf(v.y)+__expf(v.z)+__expf(v.w);
  }
  for (int off=32; off; off>>=1) s += __shfl_xor(s, off);
  if ((tid&63)==0) red[tid>>6] = s;
  __syncthreads();
  float L = logf(red[0]+red[1]+red[2]+red[3]);
  for (int i = tid*4; i < 32000; i += 1024){
    float4 v = *(float4*)(p+i);
    v.x-=L; v.y-=L; v.z-=L; v.w-=L;
    *(float4*)(p+i) = v;
  }
}

extern "C" void kernel_launch(void* const* d_in, const int* in_sizes, int n_in,
                              void* d_out, int out_size, void* d_ws, size_t ws_size,
                              hipStream_t stream){
  const float* enc = (const float*)d_in[0];
  const float* eh  = (const float*)d_in[1];
  const float* ec  = (const float*)d_in[2];
  const float* emb = (const float*)d_in[3];
  const float* Wq  = (const float*)d_in[4];
  const float* bq  = (const float*)d_in[5];
  const float* Wk  = (const float*)d_in[6];
  const float* bk  = (const float*)d_in[7];
  const float* Wv  = (const float*)d_in[8];
  const float* bv  = (const float*)d_in[9];
  const float* Wih = (const float*)d_in[10];
  const float* bih = (const float*)d_in[11];
  const float* Whh = (const float*)d_in[12];
  const float* bhh = (const float*)d_in[13];
  const float* Wo  = (const float*)d_in[14];
  const float* bo  = (const float*)d_in[15];

  char* ws = (char*)d_ws;
  __hip_bfloat16* encbf = (__hip_bfloat16*)(ws + o_encbf);
  __hip_bfloat16* kbf   = (__hip_bfloat16*)(ws + o_kbf);
  __hip_bfloat16* wkbf  = (__hip_bfloat16*)(ws + o_wkbf);
  __hip_bfloat16* wvbf  = (__hip_bfloat16*)(ws + o_wvbf);
  __hip_bfloat16* wqtbf = (__hip_bfloat16*)(ws + o_wqtbf);
  __hip_bfloat16* vt    = (__hip_bfloat16*)(ws + o_vt);
  __hip_bfloat16* woutbf= (__hip_bfloat16*)(ws + o_wout);
  __hip_bfloat16* kq    = (__hip_bfloat16*)(ws + o_kq);
  __hip_bfloat16* vbf   = (__hip_bfloat16*)(ws + o_vbf);
  __hip_bfloat16* wih2  = (__hip_bfloat16*)(ws + o_wih2);
  __hip_bfloat16* whhbf = (__hip_bfloat16*)(ws + o_whh);
  __hip_bfloat16* hall  = (__hip_bfloat16*)(ws + o_hall);
  float* gconst = (float*)(ws + o_gconst);
  float* sbp    = (float*)(ws + o_sb);
  __hip_bfloat16* hglob = (__hip_bfloat16*)(ws + o_hg);
  __hip_bfloat16* ctxn  = (__hip_bfloat16*)(ws + o_ctxn);
  float* eg     = (float*)(ws + o_eg);
  unsigned* bars= (unsigned*)(ws + o_bar);
  float* outP   = (float*)d_out;
  float* outH   = outP + 65536000;
  float* outC   = outH + 16384;

  // ---- precompute ----
  k_convert<<<1024,256,0,stream>>>(enc, encbf, 8388608);
  k_convert<<<256,256,0,stream>>>(Wk, wkbf, 1048576);
  k_convert<<<256,256,0,stream>>>(Wv, wvbf, 1048576);
  k_tcvt<<<dim3(16,16),256,0,stream>>>(Wq, wqtbf);
  k_gemm<0><<<dim3(8,64),256,0,stream>>>(encbf, wkbf, bk, kbf, 8192,1024,1024, 1.f);
  k_gemm<0><<<dim3(8,64),256,0,stream>>>(encbf, wvbf, bv, vbf, 8192,1024,1024, 1.f);
  k_gemm<0><<<dim3(8,64),256,0,stream>>>(kbf, wqtbf, (const float*)nullptr, kq, 8192,1024,1024, 0.03125f);
  k_vtrans<<<dim3(16,8,16),256,0,stream>>>(vbf, vt);
  k_sb<<<2048,256,0,stream>>>(kbf, bq, sbp);
  k_extract<<<1024,256,0,stream>>>(Wih, wih2);
  k_convert<<<1024,256,0,stream>>>(Whh, whhbf, 4194304);
  k_gconst<<<1024,256,0,stream>>>(emb, Wih, bih, bhh, gconst);
  k_init<<<64,256,0,stream>>>(eh, hglob, bars);

  // ---- recurrence: persistent kernel, 4 independent groups ----
  {
    const __hip_bfloat16* a_kq = kq; const __hip_bfloat16* a_vt = vt;
    const float* a_sb = sbp; const __hip_bfloat16* a_whh = whhbf;
    const __hip_bfloat16* a_wih = wih2; const float* a_gc = gconst;
    const float* a_ec = ec;
    __hip_bfloat16* a_hg = hglob; float* a_eg = eg;
    __hip_bfloat16* a_cx = ctxn; __hip_bfloat16* a_ha = hall;
    float* a_oh = outH; float* a_oc = outC; unsigned* a_bar = bars;
    void* args[] = { &a_kq, &a_vt, &a_sb, &a_whh, &a_wih, &a_gc, &a_ec,
                     &a_hg, &a_eg, &a_cx, &a_ha, &a_oh, &a_oc, &a_bar };
    hipError_t err = hipLaunchCooperativeKernel((void*)k_decode, dim3(256), dim3(256),
                                                args, 0u, stream);
    if (err != hipSuccess){
      k_decode<<<256,256,0,stream>>>(kq, vt, sbp, whhbf, wih2, gconst, ec,
                                     hglob, eg, ctxn, hall, outH, outC, bars);
    }
  }

  // ---- logits + log-softmax ----
  k_convert<<<2048,256,0,stream>>>(Wo, woutbf, 32768000);
  k_gemm<1><<<dim3(250,16),256,0,stream>>>(hall, woutbf, bo, d_out, 2048,32000,1024, 1.f);
  k_logsm<<<2048,256,0,stream>>>(outP);
}

// Round 6
// 2733.362 us; speedup vs baseline: 2.7273x; 1.0321x over previous
//
#include <hip/hip_runtime.h>
#include <hip/hip_bf16.h>
#include <math.h>

typedef short short8 __attribute__((ext_vector_type(8)));
typedef short short4v __attribute__((ext_vector_type(4)));
typedef float f32x4 __attribute__((ext_vector_type(4)));
typedef unsigned long long u64;

#define DEVI __device__ __forceinline__

DEVI float bf2f(short s){ union{unsigned u; float f;} x; x.u = ((unsigned)(unsigned short)s) << 16; return x.f; }

// system-scope relaxed (sc0 sc1: bypass L1/L2 to coherent point) — NO fences anywhere
DEVI void st_u32v(unsigned* p, unsigned v){ __hip_atomic_store(p, v, __ATOMIC_RELAXED, __HIP_MEMORY_SCOPE_SYSTEM); }
DEVI u64  ld_u64v(const u64* p){ return __hip_atomic_load(p, __ATOMIC_RELAXED, __HIP_MEMORY_SCOPE_SYSTEM); }
DEVI unsigned bfbits(float f){ __hip_bfloat16 h = __float2bfloat16(f); unsigned short b; __builtin_memcpy(&b,&h,2); return (unsigned)b; }

// V=32000 H=1024 S=512 B=16 T=128, SOS=1
// ws layout (bytes)
constexpr size_t o_wout   = 0;                          // bf16 [32000*1024]
constexpr size_t o_encbf  = 0;                          // overlay (dead before wout used)
constexpr size_t o_kbf    = 16777216;                   // overlay
constexpr size_t o_wkbf   = 33554432;                   // overlay
constexpr size_t o_wvbf   = 35651584;                   // overlay
constexpr size_t o_wqtbf  = 37748736;                   // overlay
constexpr size_t o_vt     = 41943040;                   // overlay: bf16 VT [16][1024][512]
constexpr size_t o_kq     = 65536000;                   // bf16 [8192*1024]
constexpr size_t o_vbf    = o_kq    + 16777216;         // bf16 [8192*1024]
constexpr size_t o_wih2   = o_vbf   + 16777216;         // bf16 [4096*1024]
constexpr size_t o_whh    = o_wih2  + 8388608;          // bf16 [4096*1024]
constexpr size_t o_hall   = o_whh   + 8388608;          // bf16 [2048*1024]
constexpr size_t o_gconst = o_hall  + 4194304;          // f32 [4096]
constexpr size_t o_sb     = o_gconst+ 16384;            // f32 [8192]
constexpr size_t o_hg     = o_sb    + 32768;            // u32 [16*1024]  h  (bf16|tag<<16)
constexpr size_t o_ctxn   = o_hg    + 65536;            // u32 [16*1024]  ctx (bf16|tag<<16)
constexpr size_t o_eg     = o_ctxn  + 65536;            // u32 [16*512]   e  (bf16|tag<<16)

// ---------------- elementwise converts ----------------
__global__ void k_convert(const float* __restrict__ src, __hip_bfloat16* __restrict__ dst, int n){
  int i = (blockIdx.x*blockDim.x + threadIdx.x)*4;
  int stride = gridDim.x*blockDim.x*4;
  for (; i < n; i += stride){
    float4 v = *(const float4*)(src+i);
    __hip_bfloat16 o[4] = {__float2bfloat16(v.x),__float2bfloat16(v.y),__float2bfloat16(v.z),__float2bfloat16(v.w)};
    *(short4v*)(dst+i) = *(const short4v*)o;
  }
}

// Wq [1024][1024] f32 -> WqT bf16 (dst[h][d] = src[d][h])
__global__ void k_tcvt(const float* __restrict__ src, __hip_bfloat16* __restrict__ dst){
  __shared__ float tile[64][65];
  int i0 = blockIdx.y*64, j0 = blockIdx.x*64;
  int tr = threadIdx.x >> 6, tc = threadIdx.x & 63;
  for (int p=0;p<16;p++){ int r = p*4 + tr; tile[r][tc] = src[(size_t)(i0+r)*1024 + j0+tc]; }
  __syncthreads();
  for (int p=0;p<16;p++){ int r = p*4 + tr; dst[(size_t)(j0+r)*1024 + i0+tc] = __float2bfloat16(tile[tc][r]); }
}

// Wih2[r][c] = W_ih[r][1024+c], r<4096
__global__ void k_extract(const float* __restrict__ src, __hip_bfloat16* __restrict__ dst){
  int i = blockIdx.x*blockDim.x + threadIdx.x;
  int stride = gridDim.x*blockDim.x;
  for (; i < 4096*1024; i += stride){
    int r = i >> 10, c = i & 1023;
    dst[i] = __float2bfloat16(src[((size_t)r << 11) + 1024 + c]);
  }
}

// init h words (tag 0) and clear ctx+e tag words
__global__ void k_init(const float* __restrict__ eh, unsigned* __restrict__ h2,
                       unsigned* __restrict__ zbase){
  int i = blockIdx.x*blockDim.x + threadIdx.x;
  if (i < 16384) h2[i] = bfbits(eh[i]);       // tag = 0
  if (i < 24576) zbase[i] = 0u;               // ctx2 (16384) + eg (8192)
}

// gate_const[n] = b_ih[n] + b_hh[n] + emb[SOS]·W_ih[n, 0:1024]
__global__ void k_gconst(const float* __restrict__ emb, const float* __restrict__ Wih,
                         const float* __restrict__ bih, const float* __restrict__ bhh,
                         float* __restrict__ gc){
  int w = threadIdx.x >> 6, lane = threadIdx.x & 63;
  int n = blockIdx.x*4 + w;
  const float* er = emb + 1024;  // SOS = 1
  const float* wr = Wih + (size_t)n*2048;
  float acc = 0.f;
  for (int q=0;q<16;q++){ int k = lane*16+q; acc += er[k]*wr[k]; }
  for (int off=32; off; off>>=1) acc += __shfl_xor(acc, off);
  if (lane==0) gc[n] = acc + bih[n] + bhh[n];
}

// sb[r] = (bq · K[r,:]) / 32
__global__ void k_sb(const __hip_bfloat16* __restrict__ Kb, const float* __restrict__ bq,
                     float* __restrict__ sb){
  int w = threadIdx.x >> 6, lane = threadIdx.x & 63;
  int r = blockIdx.x*4 + w;
  const __hip_bfloat16* kr = Kb + (size_t)r*1024;
  float acc = 0.f;
  for (int q=0;q<16;q++){ int k = lane*16+q; acc += __bfloat162float(kr[k])*bq[k]; }
  for (int off=32; off; off>>=1) acc += __shfl_xor(acc, off);
  if (lane==0) sb[r] = acc * 0.03125f;
}

// V [16*512][1024] -> VT [16][1024][512]
__global__ void k_vtrans(const __hip_bfloat16* __restrict__ V, __hip_bfloat16* __restrict__ VT){
  __shared__ short t[64][65];
  int b = blockIdx.z, s0 = blockIdx.y*64, h0 = blockIdx.x*64;
  int r = threadIdx.x >> 6, c = threadIdx.x & 63;
  const short* vp = (const short*)V + ((size_t)(b*512 + s0))*1024 + h0;
  #pragma unroll
  for (int p=0;p<16;p++) t[p*4+r][c] = vp[(size_t)(p*4+r)*1024 + c];
  __syncthreads();
  short* op = (short*)VT + ((size_t)(b*1024 + h0))*512 + s0;
  #pragma unroll
  for (int p=0;p<16;p++) op[(size_t)(p*4+r)*512 + c] = t[c][p*4+r];
}

// ---------------- GEMM: C = scale*(A @ B^T) + bias ----------------
template<int EPI>
__global__ __launch_bounds__(256) void k_gemm(const __hip_bfloat16* __restrict__ A,
    const __hip_bfloat16* __restrict__ Bm, const float* __restrict__ bias,
    void* __restrict__ Cp, int M, int N, int K, float scale){
  __shared__ __hip_bfloat16 sA[128*40];
  __shared__ __hip_bfloat16 sB[128*40];
  int tid = threadIdx.x;
  int lane = tid & 63, w = tid >> 6;
  int wr = w >> 1, wc = w & 1;
  int m0 = blockIdx.y*128, n0 = blockIdx.x*128;
  int lrow = lane & 15, lk = lane >> 4;
  f32x4 acc[4][4] = {};
  for (int k0 = 0; k0 < K; k0 += 32){
    __syncthreads();
    #pragma unroll
    for (int l0 = 0; l0 < 1024; l0 += 256){
      int l = l0 + tid;
      int half = l >> 9;
      int ch = l & 511;
      int row = ch >> 2, seg = ch & 3;
      const __hip_bfloat16* src = half ? (Bm + (size_t)(n0+row)*K + k0 + seg*8)
                                       : (A  + (size_t)(m0+row)*K + k0 + seg*8);
      __hip_bfloat16* dst = (half ? sB : sA) + row*40 + seg*8;
      *(short8*)dst = *(const short8*)src;
    }
    __syncthreads();
    short8 af[4], bfq[4];
    #pragma unroll
    for (int mi=0;mi<4;mi++) af[mi]  = *(short8*)(sA + (wr*64+mi*16+lrow)*40 + lk*8);
    #pragma unroll
    for (int ni=0;ni<4;ni++) bfq[ni] = *(short8*)(sB + (wc*64+ni*16+lrow)*40 + lk*8);
    #pragma unroll
    for (int mi=0;mi<4;mi++)
      #pragma unroll
      for (int ni=0;ni<4;ni++)
        acc[mi][ni] = __builtin_amdgcn_mfma_f32_16x16x32_bf16(af[mi], bfq[ni], acc[mi][ni], 0,0,0);
  }
  int crow0 = (lane>>4)*4;
  int ccol = lane & 15;
  #pragma unroll
  for (int mi=0;mi<4;mi++)
    #pragma unroll
    for (int ni=0;ni<4;ni++){
      int gn = n0 + wc*64 + ni*16 + ccol;
      float bv = bias ? bias[gn] : 0.0f;
      #pragma unroll
      for (int j=0;j<4;j++){
        int gm = m0 + wr*64 + mi*16 + crow0 + j;
        float v = acc[mi][ni][j]*scale + bv;
        if (EPI==0){
          ((__hip_bfloat16*)Cp)[(size_t)gm*N + gn] = __float2bfloat16(v);
        } else {
          int tt = gm >> 4, bb = gm & 15;
          ((float*)Cp)[(size_t)(bb*128+tt)*N + gn] = v;
        }
      }
    }
}

// ---------------- persistent decoder: tag-dataflow, no barriers ----------------
// 4 groups of 64 blocks, group g owns batches 4g..4g+3.
// Block roles (as R5): attention (b, chunk): 32 score rows + 64 ctx dims; gates j0: 64 outputs.
// All cross-block words are u32 = bf16 | tag<<16. Tags: h version st has tag st
// (init h = tag 0); e & ctx produced in step st carry tag st+1.
__global__ __launch_bounds__(256, 1) void k_decode(
    const __hip_bfloat16* __restrict__ KQ, const __hip_bfloat16* __restrict__ VT,
    const float* __restrict__ sb, const __hip_bfloat16* __restrict__ Whh,
    const __hip_bfloat16* __restrict__ Wih2, const float* __restrict__ gconst,
    const float* __restrict__ ec,
    unsigned* __restrict__ h2v, unsigned* __restrict__ egv,
    unsigned* __restrict__ ctx2v, __hip_bfloat16* __restrict__ hall,
    float* __restrict__ outH, float* __restrict__ outC)
{
  __shared__ __attribute__((aligned(16))) __hip_bfloat16 h4L[4][1032];
  __shared__ __attribute__((aligned(16))) float eL[528];
  __shared__ __attribute__((aligned(16))) float sPf[1024];
  __shared__ __attribute__((aligned(16))) __hip_bfloat16 sCtx[64];
  __shared__ float sSb[32];
  __shared__ float sGc[64];
  __shared__ float sRed[4];

  const int tid = threadIdx.x;
  const int lane = tid & 63, wv = tid >> 6;
  const int l16 = lane & 15, lhi = lane >> 4;
  const int blk = blockIdx.x;
  const int xcd = blk & 7, slot = blk >> 3;
  const int grp = xcd >> 1, half = xcd & 1;
  const int bloc = half*2 + (slot >> 4);
  const int chunk = slot & 15;
  const int g4 = grp*4;
  const int b = g4 + bloc;
  const int j0 = (half*32 + slot) * 16;

  // gate-weight fragments, register-resident (as R5)
  short8 wfrag[64];
  {
    const __hip_bfloat16* wsrc = (wv < 2) ? Whh : Wih2;
    const int koff = (wv & 1) * 512;
    #pragma unroll
    for (int tt = 0; tt < 4; tt++)
      #pragma unroll
      for (int kt = 0; kt < 16; kt++)
        wfrag[tt*16+kt] = *(const short8*)(wsrc + (size_t)(tt*1024 + j0 + l16)*1024 + koff + kt*32 + lhi*8);
  }
  if (tid < 32) sSb[tid] = sb[b*512 + chunk*32 + tid];
  if (tid < 64) sGc[(tid>>4)*16 + (tid&15)] = gconst[(tid>>4)*1024 + j0 + (tid&15)];
  float creg = 0.f;
  if (tid < 64) creg = ec[(size_t)(g4 + (tid>>4))*1024 + j0 + (tid&15)];

  const __hip_bfloat16* kqBlk = KQ + ((size_t)(b*512 + chunk*32))*1024;
  const int ar = (l16 < 4) ? l16 : 3;
  const short8 zfrag = {};
  f32x4 gacc[4] = {};

  for (int st = 0; st < 128; ++st){
    const unsigned wantH = (unsigned)st;
    const unsigned wantE = (unsigned)(st+1);
    const unsigned wantC = (unsigned)(st+1);

    // ---- A1: poll+stage OWN batch h (4 words/thread) ----
    {
      const u64* s0 = (const u64*)(h2v + (size_t)b*1024) + tid*2;
      u64 a0, a1; bool ok;
      do {
        a0 = ld_u64v(s0); a1 = ld_u64v(s0+1);
        ok = (((unsigned)a0>>16)==wantH) && ((unsigned)(a0>>48)==wantH)
          && (((unsigned)a1>>16)==wantH) && ((unsigned)(a1>>48)==wantH);
      } while(!ok);
      short4v o = { (short)(unsigned)a0, (short)(a0>>32), (short)(unsigned)a1, (short)(a1>>32) };
      *(short4v*)&h4L[bloc][tid*4] = o;
    }
    __syncthreads();
    // ---- scores -> e (bf16|tag) ----
    {
      int row = tid >> 3, kx = tid & 7;
      const __hip_bfloat16* kp = kqBlk + (size_t)row*1024 + kx*8;
      float acc = 0.f;
      #pragma unroll
      for (int q = 0; q < 16; q++){
        short8 kv = *(const short8*)(kp + q*64);
        short8 hv = *(const short8*)&h4L[bloc][kx*8 + q*64];
        #pragma unroll
        for (int e2 = 0; e2 < 8; e2++) acc += bf2f(hv[e2]) * bf2f(kv[e2]);
      }
      acc += __shfl_xor(acc, 1); acc += __shfl_xor(acc, 2); acc += __shfl_xor(acc, 4);
      if (kx == 0)
        st_u32v(&egv[b*512 + chunk*32 + row], bfbits(expf(acc + sSb[row])) | (wantE<<16));
    }
    // ---- A2: poll+stage other 3 batches (overlaps e flight) ----
    {
      const u64* sp0 = (const u64*)(h2v + (size_t)(g4 + ((bloc+1)&3))*1024) + tid*2;
      const u64* sp1 = (const u64*)(h2v + (size_t)(g4 + ((bloc+2)&3))*1024) + tid*2;
      const u64* sp2 = (const u64*)(h2v + (size_t)(g4 + ((bloc+3)&3))*1024) + tid*2;
      u64 v[6]; bool ok;
      do {
        v[0]=ld_u64v(sp0); v[1]=ld_u64v(sp0+1);
        v[2]=ld_u64v(sp1); v[3]=ld_u64v(sp1+1);
        v[4]=ld_u64v(sp2); v[5]=ld_u64v(sp2+1);
        ok = true;
        #pragma unroll
        for (int i=0;i<6;i++) ok &= (((unsigned)v[i]>>16)==wantH) && ((unsigned)(v[i]>>48)==wantH);
      } while(!ok);
      #pragma unroll
      for (int rr=0;rr<3;rr++){
        int rl = (bloc+rr+1)&3;
        short4v o = { (short)(unsigned)v[rr*2], (short)(v[rr*2]>>32),
                      (short)(unsigned)v[rr*2+1], (short)(v[rr*2+1]>>32) };
        *(short4v*)&h4L[rl][tid*4] = o;
      }
    }
    __syncthreads();
    // ---- h-part gate MFMA (overlaps e flight) ----
    if (wv < 2){
      const int ko = (wv & 1) * 512;
      #pragma unroll
      for (int kt = 0; kt < 16; kt++){
        short8 a = *(const short8*)&h4L[ar][ko + kt*32 + lhi*8];
        a = (l16 < 4) ? a : zfrag;
        #pragma unroll
        for (int tt = 0; tt < 4; tt++)
          gacc[tt] = __builtin_amdgcn_mfma_f32_16x16x32_bf16(a, wfrag[tt*16+kt], gacc[tt], 0,0,0);
      }
    }

    // ---- B: poll full e[b] (2 words/thread), L, ctx slice ----
    {
      const u64* s = (const u64*)(egv + b*512) + tid;
      u64 v;
      do { v = ld_u64v(s); }
      while(!((((unsigned)v>>16)==wantE) && ((unsigned)(v>>48)==wantE)));
      float e0 = bf2f((short)(unsigned)v), e1 = bf2f((short)(v>>32));
      int i0 = tid*2;
      int pad = (i0>>7)<<2;
      eL[i0 + pad] = e0; eL[i0+1 + pad] = e1;
      float lp = e0 + e1;
      for (int off=32; off; off>>=1) lp += __shfl_xor(lp, off);
      if (lane == 0) sRed[wv] = lp;
    }
    __syncthreads();
    {
      float Linv = 1.0f/(sRed[0]+sRed[1]+sRed[2]+sRed[3]);
      int hloc = tid >> 2, sc = (tid & 3)*128;
      const __hip_bfloat16* vp = VT + ((size_t)(b*1024 + chunk*64 + hloc))*512 + sc;
      const float* ep = eL + sc + ((sc>>7)<<2);
      float a = 0.f;
      #pragma unroll
      for (int q = 0; q < 16; q++){
        short8 vv = *(const short8*)(vp + q*8);
        float4 e0 = *(const float4*)(ep + q*8);
        float4 e1 = *(const float4*)(ep + q*8 + 4);
        a += e0.x*bf2f(vv[0]) + e0.y*bf2f(vv[1]) + e0.z*bf2f(vv[2]) + e0.w*bf2f(vv[3]);
        a += e1.x*bf2f(vv[4]) + e1.y*bf2f(vv[5]) + e1.z*bf2f(vv[6]) + e1.w*bf2f(vv[7]);
      }
      a += __shfl_xor(a, 1); a += __shfl_xor(a, 2);
      if ((tid & 3) == 0) sCtx[hloc] = __float2bfloat16(a * Linv);
    }
    __syncthreads();
    if (tid < 64){
      unsigned short cbts; __builtin_memcpy(&cbts, &sCtx[tid], 2);
      st_u32v(&ctx2v[(size_t)b*1024 + chunk*64 + tid], (unsigned)cbts | (wantC<<16));
    }

    // ---- C: poll+stage ctx (16 words/thread), ctx-part MFMA, gates, LSTM ----
    {
      int r = tid >> 6, c0 = (tid & 63)*16;
      const u64* s = (const u64*)(ctx2v + (size_t)(g4 + r)*1024 + c0);
      u64 v[8]; bool ok;
      do {
        ok = true;
        #pragma unroll
        for (int i=0;i<8;i++) v[i] = ld_u64v(s+i);
        #pragma unroll
        for (int i=0;i<8;i++) ok &= (((unsigned)v[i]>>16)==wantC) && ((unsigned)(v[i]>>48)==wantC);
      } while(!ok);
      short8 o0, o1;
      #pragma unroll
      for (int i=0;i<4;i++){ o0[2*i] = (short)(unsigned)v[i]; o0[2*i+1] = (short)(v[i]>>32); }
      #pragma unroll
      for (int i=0;i<4;i++){ o1[2*i] = (short)(unsigned)v[4+i]; o1[2*i+1] = (short)(v[4+i]>>32); }
      *(short8*)&h4L[r][c0] = o0;
      *(short8*)&h4L[r][c0+8] = o1;
    }
    __syncthreads();
    if (wv >= 2){
      const int ko = (wv & 1) * 512;
      #pragma unroll
      for (int kt = 0; kt < 16; kt++){
        short8 a = *(const short8*)&h4L[ar][ko + kt*32 + lhi*8];
        a = (l16 < 4) ? a : zfrag;
        #pragma unroll
        for (int tt = 0; tt < 4; tt++)
          gacc[tt] = __builtin_amdgcn_mfma_f32_16x16x32_bf16(a, wfrag[tt*16+kt], gacc[tt], 0,0,0);
      }
    }
    if (lhi == 0){
      #pragma unroll
      for (int tt = 0; tt < 4; tt++)
        *(f32x4*)&sPf[(wv*64 + tt*16 + l16)*4] = gacc[tt];
    }
    #pragma unroll
    for (int tt = 0; tt < 4; tt++) gacc[tt] = (f32x4){0.f,0.f,0.f,0.f};
    __syncthreads();
    if (tid < 64){
      int bb = tid >> 4, jj = tid & 15;
      float gv[4];
      #pragma unroll
      for (int tt = 0; tt < 4; tt++){
        float s = sGc[tt*16 + jj];
        #pragma unroll
        for (int w2 = 0; w2 < 4; w2++) s += sPf[(w2*64 + tt*16 + jj)*4 + bb];
        gv[tt] = s;
      }
      float si = 1.f/(1.f+expf(-gv[0]));
      float sf = 1.f/(1.f+expf(-gv[1]));
      float so = 1.f/(1.f+expf(-gv[3]));
      float c2 = sf*creg + si*tanhf(gv[2]);
      float h2 = so*tanhf(c2);
      creg = c2;
      int gb = g4 + bb;
      __hip_bfloat16 hbv = __float2bfloat16(h2);
      unsigned short hbits; __builtin_memcpy(&hbits, &hbv, 2);
      st_u32v(&h2v[(size_t)gb*1024 + j0 + jj], (unsigned)hbits | ((unsigned)(st+1)<<16));
      hall[((size_t)(st*16 + gb))*1024 + j0 + jj] = hbv;
      if (st == 127){ outH[gb*1024 + j0 + jj] = h2; outC[gb*1024 + j0 + jj] = c2; }
    }
  }
}

// ---------------- in-place log-softmax over rows of 32000 ----------------
__global__ __launch_bounds__(256) void k_logsm(float* __restrict__ out){
  int row = blockIdx.x;
  float* p = out + (size_t)row*32000;
  int tid = threadIdx.x;
  __shared__ float red[4];
  float s = 0.f;
  for (int i = tid*4; i < 32000; i += 1024){
    float4 v = *(float4*)(p+i);
    s += __expf(v.x)+__expf(v.y)+__expf(v.z)+__expf(v.w);
  }
  for (int off=32; off; off>>=1) s += __shfl_xor(s, off);
  if ((tid&63)==0) red[tid>>6] = s;
  __syncthreads();
  float L = logf(red[0]+red[1]+red[2]+red[3]);
  for (int i = tid*4; i < 32000; i += 1024){
    float4 v = *(float4*)(p+i);
    v.x-=L; v.y-=L; v.z-=L; v.w-=L;
    *(float4*)(p+i) = v;
  }
}

extern "C" void kernel_launch(void* const* d_in, const int* in_sizes, int n_in,
                              void* d_out, int out_size, void* d_ws, size_t ws_size,
                              hipStream_t stream){
  const float* enc = (const float*)d_in[0];
  const float* eh  = (const float*)d_in[1];
  const float* ec  = (const float*)d_in[2];
  const float* emb = (const float*)d_in[3];
  const float* Wq  = (const float*)d_in[4];
  const float* bq  = (const float*)d_in[5];
  const float* Wk  = (const float*)d_in[6];
  const float* bk  = (const float*)d_in[7];
  const float* Wv  = (const float*)d_in[8];
  const float* bv  = (const float*)d_in[9];
  const float* Wih = (const float*)d_in[10];
  const float* bih = (const float*)d_in[11];
  const float* Whh = (const float*)d_in[12];
  const float* bhh = (const float*)d_in[13];
  const float* Wo  = (const float*)d_in[14];
  const float* bo  = (const float*)d_in[15];

  char* ws = (char*)d_ws;
  __hip_bfloat16* encbf = (__hip_bfloat16*)(ws + o_encbf);
  __hip_bfloat16* kbf   = (__hip_bfloat16*)(ws + o_kbf);
  __hip_bfloat16* wkbf  = (__hip_bfloat16*)(ws + o_wkbf);
  __hip_bfloat16* wvbf  = (__hip_bfloat16*)(ws + o_wvbf);
  __hip_bfloat16* wqtbf = (__hip_bfloat16*)(ws + o_wqtbf);
  __hip_bfloat16* vt    = (__hip_bfloat16*)(ws + o_vt);
  __hip_bfloat16* woutbf= (__hip_bfloat16*)(ws + o_wout);
  __hip_bfloat16* kq    = (__hip_bfloat16*)(ws + o_kq);
  __hip_bfloat16* vbf   = (__hip_bfloat16*)(ws + o_vbf);
  __hip_bfloat16* wih2  = (__hip_bfloat16*)(ws + o_wih2);
  __hip_bfloat16* whhbf = (__hip_bfloat16*)(ws + o_whh);
  __hip_bfloat16* hall  = (__hip_bfloat16*)(ws + o_hall);
  float* gconst = (float*)(ws + o_gconst);
  float* sbp    = (float*)(ws + o_sb);
  unsigned* h2v   = (unsigned*)(ws + o_hg);
  unsigned* ctx2v = (unsigned*)(ws + o_ctxn);
  unsigned* egv   = (unsigned*)(ws + o_eg);
  float* outP   = (float*)d_out;
  float* outH   = outP + 65536000;
  float* outC   = outH + 16384;

  // ---- precompute ----
  k_convert<<<1024,256,0,stream>>>(enc, encbf, 8388608);
  k_convert<<<256,256,0,stream>>>(Wk, wkbf, 1048576);
  k_convert<<<256,256,0,stream>>>(Wv, wvbf, 1048576);
  k_tcvt<<<dim3(16,16),256,0,stream>>>(Wq, wqtbf);
  k_gemm<0><<<dim3(8,64),256,0,stream>>>(encbf, wkbf, bk, kbf, 8192,1024,1024, 1.f);
  k_gemm<0><<<dim3(8,64),256,0,stream>>>(encbf, wvbf, bv, vbf, 8192,1024,1024, 1.f);
  k_gemm<0><<<dim3(8,64),256,0,stream>>>(kbf, wqtbf, (const float*)nullptr, kq, 8192,1024,1024, 0.03125f);
  k_vtrans<<<dim3(16,8,16),256,0,stream>>>(vbf, vt);
  k_sb<<<2048,256,0,stream>>>(kbf, bq, sbp);
  k_extract<<<1024,256,0,stream>>>(Wih, wih2);
  k_convert<<<1024,256,0,stream>>>(Whh, whhbf, 4194304);
  k_gconst<<<1024,256,0,stream>>>(emb, Wih, bih, bhh, gconst);
  k_init<<<96,256,0,stream>>>(eh, h2v, ctx2v);   // ctx2v..+24576 u32 covers ctx2+eg

  // ---- recurrence: persistent tag-dataflow kernel ----
  {
    const __hip_bfloat16* a_kq = kq; const __hip_bfloat16* a_vt = vt;
    const float* a_sb = sbp; const __hip_bfloat16* a_whh = whhbf;
    const __hip_bfloat16* a_wih = wih2; const float* a_gc = gconst;
    const float* a_ec = ec;
    unsigned* a_h = h2v; unsigned* a_e = egv; unsigned* a_c = ctx2v;
    __hip_bfloat16* a_ha = hall;
    float* a_oh = outH; float* a_oc = outC;
    void* args[] = { &a_kq, &a_vt, &a_sb, &a_whh, &a_wih, &a_gc, &a_ec,
                     &a_h, &a_e, &a_c, &a_ha, &a_oh, &a_oc };
    hipError_t err = hipLaunchCooperativeKernel((void*)k_decode, dim3(256), dim3(256),
                                                args, 0u, stream);
    if (err != hipSuccess){
      k_decode<<<256,256,0,stream>>>(kq, vt, sbp, whhbf, wih2, gconst, ec,
                                     h2v, egv, ctx2v, hall, outH, outC);
    }
  }

  // ---- logits + log-softmax ----
  k_convert<<<2048,256,0,stream>>>(Wo, woutbf, 32768000);
  k_gemm<1><<<dim3(250,16),256,0,stream>>>(hall, woutbf, bo, d_out, 2048,32000,1024, 1.f);
  k_logsm<<<2048,256,0,stream>>>(outP);
}